// Round 1
// baseline (4836.788 us; speedup 1.0000x reference)
//
#include <hip/hip_runtime.h>

#define CONC_N 2000
#define ITEM_N 20000
#define STU_N  50000
#define NE_CC  40000
#define NE_IC  80000
#define NE_SI  1000000

// ---------------- misc small kernels ----------------

__global__ void zero_ints(int* __restrict__ p, int n) {
  int i = blockIdx.x * blockDim.x + threadIdx.x;
  if (i < n) p[i] = 0;
}

// v[k] = sum_j W[j*128+k] * a[j]   (projected attention vector W^T a)
struct ProjDesc { const float* W; const float* a; float* out; };
struct ProjDescs { ProjDesc d[10]; };
__global__ void proj_vecs(ProjDescs P) {
  ProjDesc d = P.d[blockIdx.x];
  int k = threadIdx.x;  // 128 threads
  float acc = 0.f;
  for (int j = 0; j < 128; ++j) acc += d.W[j * 128 + k] * d.a[j];
  d.out[k] = acc;
}

// out[r] = dot(x[r,:], v)  -- wave per row
struct RowDotDesc { const float* x; const float* v; float* out; int n; };
struct RowDotDescs { RowDotDesc d[12]; };
__global__ void rowdots(RowDotDescs P) {
  RowDotDesc d = P.d[blockIdx.y];
  int lane = threadIdx.x & 63;
  int wid = (blockIdx.x * blockDim.x + threadIdx.x) >> 6;
  int nw = (gridDim.x * blockDim.x) >> 6;
  float v0 = d.v[lane], v1 = d.v[64 + lane];
  for (int r = wid; r < d.n; r += nw) {
    float a = d.x[r * 128 + lane] * v0 + d.x[r * 128 + 64 + lane] * v1;
    #pragma unroll
    for (int o = 32; o; o >>= 1) a += __shfl_xor(a, o);
    if (lane == 0) d.out[r] = a;
  }
}

// ---------------- CSR build ----------------

struct GraphDesc {
  const int* dst; const int* src;
  int* cnt; int* offs; int* cur; int* srcs;
  int E; int n;
};
struct GraphDescs { GraphDesc g[5]; };

__global__ void hist5(GraphDescs G) {
  GraphDesc g = G.g[blockIdx.y];
  for (int e = blockIdx.x * blockDim.x + threadIdx.x; e < g.E;
       e += gridDim.x * blockDim.x)
    atomicAdd(&g.cnt[g.dst[e]], 1);
}

__global__ __launch_bounds__(1024) void scan5(GraphDescs G) {
  GraphDesc g = G.g[blockIdx.x];
  __shared__ int wsum[16];
  __shared__ int ctot;
  int tid = threadIdx.x, lane = tid & 63, wv = tid >> 6;
  int run = 0;
  for (int base = 0; base < g.n; base += 1024) {
    int i = base + tid;
    int v = (i < g.n) ? g.cnt[i] : 0;
    int incl = v;
    #pragma unroll
    for (int o = 1; o < 64; o <<= 1) {
      int y = __shfl_up(incl, o);
      if (lane >= o) incl += y;
    }
    if (lane == 63) wsum[wv] = incl;
    __syncthreads();
    if (tid == 0) {
      int a = 0;
      #pragma unroll
      for (int w = 0; w < 16; ++w) { int t = wsum[w]; wsum[w] = a; a += t; }
      ctot = a;
    }
    __syncthreads();
    int excl = run + wsum[wv] + incl - v;
    if (i < g.n) { g.offs[i] = excl; g.cur[i] = excl; }
    run += ctot;
    __syncthreads();
  }
  if (tid == 0) g.offs[g.n] = run;
}

__global__ void fill5(GraphDescs G) {
  GraphDesc g = G.g[blockIdx.y];
  for (int e = blockIdx.x * blockDim.x + threadIdx.x; e < g.E;
       e += gridDim.x * blockDim.x) {
    int pos = atomicAdd(&g.cur[g.dst[e]], 1);
    g.srcs[pos] = g.src[e];
  }
}

// ---------------- GEMM: Y[n,128] = X[n,128] @ W[128,128]^T ----------------

__global__ __launch_bounds__(256) void gemm128(const float* __restrict__ X,
                                               const float* __restrict__ W,
                                               float* __restrict__ Y, int n) {
  __shared__ float Wl[128 * 33];
  __shared__ float Xl[32 * 32];
  int tid = threadIdx.x;
  int c = tid & 127, rg = tid >> 7;
  int rowbase = blockIdx.x * 32;
  float acc[16];
  #pragma unroll
  for (int r = 0; r < 16; ++r) acc[r] = 0.f;
  for (int kc = 0; kc < 4; ++kc) {
    int k0 = kc * 32;
    #pragma unroll
    for (int i = 0; i < 4; ++i) {
      int s = tid + i * 256;            // 1024 float4 slots
      int row = s >> 3, seg = s & 7;
      const float4 wv = *(const float4*)&W[row * 128 + k0 + seg * 4];
      float* dstp = &Wl[row * 33 + seg * 4];
      dstp[0] = wv.x; dstp[1] = wv.y; dstp[2] = wv.z; dstp[3] = wv.w;
    }
    #pragma unroll
    for (int i = 0; i < 4; ++i) {
      int s = tid + i * 256;            // 1024 floats
      int row = s >> 5, kk = s & 31;
      int gr = rowbase + row;
      Xl[row * 32 + kk] = (gr < n) ? X[gr * 128 + k0 + kk] : 0.f;
    }
    __syncthreads();
    #pragma unroll
    for (int kk4 = 0; kk4 < 8; ++kk4) {
      float4 xv[16];
      #pragma unroll
      for (int r = 0; r < 16; ++r)
        xv[r] = *(const float4*)&Xl[(rg * 16 + r) * 32 + kk4 * 4];
      #pragma unroll
      for (int m = 0; m < 4; ++m) {
        float wsc = Wl[c * 33 + kk4 * 4 + m];
        #pragma unroll
        for (int r = 0; r < 16; ++r) {
          float xs = (m == 0) ? xv[r].x : (m == 1) ? xv[r].y
                   : (m == 2) ? xv[r].z : xv[r].w;
          acc[r] += xs * wsc;
        }
      }
    }
    __syncthreads();
  }
  #pragma unroll
  for (int r = 0; r < 16; ++r) {
    int gr = rowbase + rg * 16 + r;
    if (gr < n) Y[gr * 128 + c] = acc[r];
  }
}

// ---------------- GAT aggregation (wave per target) ----------------

__global__ void gat_agg(const int* __restrict__ offs, const int* __restrict__ srcs,
                        const float* __restrict__ sl, const float* __restrict__ sr,
                        const float* __restrict__ xl,
                        const float* __restrict__ base0, const float* __restrict__ base1,
                        float* __restrict__ out, int n_tgt) {
  int t = (blockIdx.x * blockDim.x + threadIdx.x) >> 6;
  if (t >= n_tgt) return;
  int lane = threadIdx.x & 63;
  int sbeg = offs[t], send = offs[t + 1];
  float srt = sr[t];
  float m = -1e30f;
  for (int i = sbeg + lane; i < send; i += 64) {
    float e = sl[srcs[i]] + srt;
    e = e > 0.f ? e : 0.2f * e;
    m = fmaxf(m, e);
  }
  #pragma unroll
  for (int o = 32; o; o >>= 1) m = fmaxf(m, __shfl_xor(m, o));
  float se = 0.f;
  for (int i = sbeg + lane; i < send; i += 64) {
    float e = sl[srcs[i]] + srt;
    e = e > 0.f ? e : 0.2f * e;
    se += __expf(e - m);
  }
  #pragma unroll
  for (int o = 32; o; o >>= 1) se += __shfl_xor(se, o);
  float inv = 1.f / (se + 1e-16f);
  float ax = 0.f, ay = 0.f;
  for (int i0 = sbeg; i0 < send; i0 += 64) {
    int cnt = min(64, send - i0);
    int s = 0; float wgt = 0.f;
    if (lane < cnt) {
      s = srcs[i0 + lane];
      float e = sl[s] + srt;
      e = e > 0.f ? e : 0.2f * e;
      wgt = __expf(e - m) * inv;
    }
    for (int j = 0; j < cnt; ++j) {
      int sj = __shfl(s, j);
      float wj = __shfl(wgt, j);
      const float2 v = *(const float2*)&xl[sj * 128 + lane * 2];
      ax += wj * v.x; ay += wj * v.y;
    }
  }
  if (base0) { const float2 b = *(const float2*)&base0[t * 128 + lane * 2]; ax += b.x; ay += b.y; }
  if (base1) { const float2 b = *(const float2*)&base1[t * 128 + lane * 2]; ax += b.x; ay += b.y; }
  float2 o2; o2.x = ax; o2.y = ay;
  *(float2*)&out[t * 128 + lane * 2] = o2;
}

// e1 + e2 fused (both on the cc graph), writes conc_fused = base + r1 + r2
__global__ void gat_agg_dual(const int* __restrict__ offs, const int* __restrict__ srcs,
                             const float* __restrict__ sl1, const float* __restrict__ sr1,
                             const float* __restrict__ xl1,
                             const float* __restrict__ sl2, const float* __restrict__ sr2,
                             const float* __restrict__ xl2,
                             const float* __restrict__ base,
                             float* __restrict__ out, int n_tgt) {
  int t = (blockIdx.x * blockDim.x + threadIdx.x) >> 6;
  if (t >= n_tgt) return;
  int lane = threadIdx.x & 63;
  int sbeg = offs[t], send = offs[t + 1];
  float srt1 = sr1[t], srt2 = sr2[t];
  float m1 = -1e30f, m2 = -1e30f;
  for (int i = sbeg + lane; i < send; i += 64) {
    int s = srcs[i];
    float e1 = sl1[s] + srt1; e1 = e1 > 0.f ? e1 : 0.2f * e1;
    float e2 = sl2[s] + srt2; e2 = e2 > 0.f ? e2 : 0.2f * e2;
    m1 = fmaxf(m1, e1); m2 = fmaxf(m2, e2);
  }
  #pragma unroll
  for (int o = 32; o; o >>= 1) {
    m1 = fmaxf(m1, __shfl_xor(m1, o));
    m2 = fmaxf(m2, __shfl_xor(m2, o));
  }
  float se1 = 0.f, se2 = 0.f;
  for (int i = sbeg + lane; i < send; i += 64) {
    int s = srcs[i];
    float e1 = sl1[s] + srt1; e1 = e1 > 0.f ? e1 : 0.2f * e1;
    float e2 = sl2[s] + srt2; e2 = e2 > 0.f ? e2 : 0.2f * e2;
    se1 += __expf(e1 - m1); se2 += __expf(e2 - m2);
  }
  #pragma unroll
  for (int o = 32; o; o >>= 1) {
    se1 += __shfl_xor(se1, o);
    se2 += __shfl_xor(se2, o);
  }
  float inv1 = 1.f / (se1 + 1e-16f), inv2 = 1.f / (se2 + 1e-16f);
  float ax = 0.f, ay = 0.f;
  for (int i0 = sbeg; i0 < send; i0 += 64) {
    int cnt = min(64, send - i0);
    int s = 0; float w1 = 0.f, w2 = 0.f;
    if (lane < cnt) {
      s = srcs[i0 + lane];
      float e1 = sl1[s] + srt1; e1 = e1 > 0.f ? e1 : 0.2f * e1;
      float e2 = sl2[s] + srt2; e2 = e2 > 0.f ? e2 : 0.2f * e2;
      w1 = __expf(e1 - m1) * inv1;
      w2 = __expf(e2 - m2) * inv2;
    }
    for (int j = 0; j < cnt; ++j) {
      int sj = __shfl(s, j);
      float wj1 = __shfl(w1, j);
      float wj2 = __shfl(w2, j);
      const float2 v1 = *(const float2*)&xl1[sj * 128 + lane * 2];
      const float2 v2 = *(const float2*)&xl2[sj * 128 + lane * 2];
      ax += wj1 * v1.x + wj2 * v2.x;
      ay += wj1 * v1.y + wj2 * v2.y;
    }
  }
  const float2 b = *(const float2*)&base[t * 128 + lane * 2];
  float2 o2; o2.x = ax + b.x; o2.y = ay + b.y;
  *(float2*)&out[t * 128 + lane * 2] = o2;
}

// ---------------- launch ----------------

extern "C" void kernel_launch(void* const* d_in, const int* in_sizes, int n_in,
                              void* d_out, int out_size, void* d_ws, size_t ws_size,
                              hipStream_t stream) {
  const float* stu_x     = (const float*)d_in[0];
  const float* item_x    = (const float*)d_in[1];
  const float* conc_x    = (const float*)d_in[2];
  const float* stu_raw_x = (const float*)d_in[3];
  const float* W_cc  = (const float*)d_in[4];
  const float* al_cc = (const float*)d_in[5];
  const float* ar_cc = (const float*)d_in[6];
  const float* W_ic  = (const float*)d_in[7];
  const float* al_ic = (const float*)d_in[8];
  const float* ar_ic = (const float*)d_in[9];
  const float* al_cce = (const float*)d_in[10];
  const float* ar_cce = (const float*)d_in[11];
  const float* al_ice = (const float*)d_in[12];
  const float* ar_ice = (const float*)d_in[13];
  const float* W_ci  = (const float*)d_in[14];
  const float* al_ci = (const float*)d_in[15];
  const float* ar_ci = (const float*)d_in[16];
  const float* W_si  = (const float*)d_in[17];
  const float* al_si = (const float*)d_in[18];
  const float* ar_si = (const float*)d_in[19];
  const float* W_is  = (const float*)d_in[22];
  const float* al_is = (const float*)d_in[23];
  const float* ar_is = (const float*)d_in[24];
  const int* cc_src  = (const int*)d_in[25];
  const int* cc_dst  = (const int*)d_in[26];
  const int* ic_item = (const int*)d_in[27];
  const int* ic_conc = (const int*)d_in[28];
  const int* si_stu  = (const int*)d_in[29];
  const int* si_item = (const int*)d_in[30];

  char* wsb = (char*)d_ws;
  size_t off = 0;
  auto alloc = [&](size_t bytes) -> void* {
    void* p = wsb + off;
    off = (off + bytes + 255) & ~(size_t)255;
    return p;
  };

  float* concWcc = (float*)alloc((size_t)CONC_N * 128 * 4);
  float* itemWic = (float*)alloc((size_t)ITEM_N * 128 * 4);
  float* concWci = (float*)alloc((size_t)CONC_N * 128 * 4);
  float* stuWsi  = (float*)alloc((size_t)STU_N  * 128 * 4);
  float* itemWis = (float*)alloc((size_t)ITEM_N * 128 * 4);
  float* c1buf   = (float*)alloc((size_t)CONC_N * 128 * 4);
  float* c2buf   = (float*)alloc((size_t)CONC_N * 128 * 4);
  float* i1buf   = (float*)alloc((size_t)ITEM_N * 128 * 4);
  float* vecs    = (float*)alloc(10 * 128 * 4);   // projected att vectors
  float* sl_cc  = (float*)alloc(CONC_N * 4);
  float* sr_cc  = (float*)alloc(CONC_N * 4);
  float* sl_ic  = (float*)alloc(ITEM_N * 4);
  float* sr_ic  = (float*)alloc(CONC_N * 4);
  float* sl_ci  = (float*)alloc(CONC_N * 4);
  float* sr_ci  = (float*)alloc(ITEM_N * 4);
  float* sl_si  = (float*)alloc(STU_N * 4);
  float* sr_si  = (float*)alloc(ITEM_N * 4);
  float* sl_is  = (float*)alloc(ITEM_N * 4);
  float* sr_is  = (float*)alloc(STU_N * 4);
  float* sl_cce = (float*)alloc(CONC_N * 4);
  float* sr_cce = (float*)alloc(CONC_N * 4);
  float* sl_ice = (float*)alloc(CONC_N * 4);
  float* sr_ice = (float*)alloc(CONC_N * 4);

  // CSR buffers: 5 graphs (cnt arrays contiguous for one zero pass)
  const int ncnt_tot = CONC_N + CONC_N + ITEM_N + ITEM_N + STU_N;  // 94000
  int* cnt_all = (int*)alloc((size_t)ncnt_tot * 4);
  int* cnt0 = cnt_all;
  int* cnt1 = cnt0 + CONC_N;
  int* cnt2 = cnt1 + CONC_N;
  int* cnt3 = cnt2 + ITEM_N;
  int* cnt4 = cnt3 + ITEM_N;
  int* offs0 = (int*)alloc((CONC_N + 1) * 4);
  int* offs1 = (int*)alloc((CONC_N + 1) * 4);
  int* offs2 = (int*)alloc((ITEM_N + 1) * 4);
  int* offs3 = (int*)alloc((ITEM_N + 1) * 4);
  int* offs4 = (int*)alloc((STU_N + 1) * 4);
  int* cur0 = (int*)alloc(CONC_N * 4);
  int* cur1 = (int*)alloc(CONC_N * 4);
  int* cur2 = (int*)alloc(ITEM_N * 4);
  int* cur3 = (int*)alloc(ITEM_N * 4);
  int* cur4 = (int*)alloc(STU_N * 4);
  int* srcs0 = (int*)alloc((size_t)NE_CC * 4);
  int* srcs1 = (int*)alloc((size_t)NE_IC * 4);
  int* srcs2 = (int*)alloc((size_t)NE_IC * 4);
  int* srcs3 = (int*)alloc((size_t)NE_SI * 4);
  int* srcs4 = (int*)alloc((size_t)NE_SI * 4);

  float* out = (float*)d_out;
  float* out_conc = out;
  float* out_item = out + (size_t)CONC_N * 128;
  float* out_stu  = out + (size_t)(CONC_N + ITEM_N) * 128;

  // 1) zero counters
  zero_ints<<<(ncnt_tot + 255) / 256, 256, 0, stream>>>(cnt_all, ncnt_tot);

  // 2) projected attention vectors
  ProjDescs P;
  P.d[0] = {W_cc, al_cc, vecs + 0 * 128};
  P.d[1] = {W_cc, ar_cc, vecs + 1 * 128};
  P.d[2] = {W_ic, al_ic, vecs + 2 * 128};
  P.d[3] = {W_ic, ar_ic, vecs + 3 * 128};
  P.d[4] = {W_ci, al_ci, vecs + 4 * 128};
  P.d[5] = {W_ci, ar_ci, vecs + 5 * 128};
  P.d[6] = {W_si, al_si, vecs + 6 * 128};
  P.d[7] = {W_si, ar_si, vecs + 7 * 128};
  P.d[8] = {W_is, al_is, vecs + 8 * 128};
  P.d[9] = {W_is, ar_is, vecs + 9 * 128};
  proj_vecs<<<10, 128, 0, stream>>>(P);

  // 3) CSR build: graphs {cc, icC, icI, siI, siS}
  GraphDescs G;
  G.g[0] = {cc_dst,  cc_src,  cnt0, offs0, cur0, srcs0, NE_CC, CONC_N};
  G.g[1] = {ic_conc, ic_item, cnt1, offs1, cur1, srcs1, NE_IC, CONC_N};
  G.g[2] = {ic_item, ic_conc, cnt2, offs2, cur2, srcs2, NE_IC, ITEM_N};
  G.g[3] = {si_item, si_stu,  cnt3, offs3, cur3, srcs3, NE_SI, ITEM_N};
  G.g[4] = {si_stu,  si_item, cnt4, offs4, cur4, srcs4, NE_SI, STU_N};
  hist5<<<dim3(1024, 5), 256, 0, stream>>>(G);
  scan5<<<5, 1024, 0, stream>>>(G);
  fill5<<<dim3(1024, 5), 256, 0, stream>>>(G);

  // 4) linear transforms (only the xl's we need to materialize)
  gemm128<<<(CONC_N + 31) / 32, 256, 0, stream>>>(conc_x, W_cc, concWcc, CONC_N);
  gemm128<<<(ITEM_N + 31) / 32, 256, 0, stream>>>(item_x, W_ic, itemWic, ITEM_N);
  gemm128<<<(CONC_N + 31) / 32, 256, 0, stream>>>(conc_x, W_ci, concWci, CONC_N);
  gemm128<<<(STU_N  + 31) / 32, 256, 0, stream>>>(stu_x,  W_si, stuWsi,  STU_N);
  gemm128<<<(ITEM_N + 31) / 32, 256, 0, stream>>>(item_x, W_is, itemWis, ITEM_N);

  // 5) per-node attention scores, batch 1
  RowDotDescs R1;
  R1.d[0]  = {conc_x,    vecs + 0 * 128, sl_cc, CONC_N};
  R1.d[1]  = {conc_x,    vecs + 1 * 128, sr_cc, CONC_N};
  R1.d[2]  = {item_x,    vecs + 2 * 128, sl_ic, ITEM_N};
  R1.d[3]  = {conc_x,    vecs + 3 * 128, sr_ic, CONC_N};
  R1.d[4]  = {conc_x,    vecs + 4 * 128, sl_ci, CONC_N};
  R1.d[5]  = {item_x,    vecs + 5 * 128, sr_ci, ITEM_N};
  R1.d[6]  = {stu_x,     vecs + 6 * 128, sl_si, STU_N};
  R1.d[7]  = {item_x,    vecs + 7 * 128, sr_si, ITEM_N};
  R1.d[8]  = {item_x,    vecs + 8 * 128, sl_is, ITEM_N};
  R1.d[9]  = {stu_raw_x, vecs + 9 * 128, sr_is, STU_N};
  R1.d[10] = {conc_x,    ar_cce,         sr_cce, CONC_N};
  R1.d[11] = {conc_x,    ar_ice,         sr_ice, CONC_N};
  rowdots<<<dim3(128, 12), 256, 0, stream>>>(R1);

  // 6) c1, c2 (inter GATs on concept targets)
  gat_agg<<<(CONC_N + 3) / 4, 256, 0, stream>>>(offs0, srcs0, sl_cc, sr_cc,
                                                concWcc, nullptr, nullptr, c1buf, CONC_N);
  gat_agg<<<(CONC_N + 3) / 4, 256, 0, stream>>>(offs1, srcs1, sl_ic, sr_ic,
                                                itemWic, nullptr, nullptr, c2buf, CONC_N);

  // 7) scores that depend on c1/c2
  RowDotDescs R2;
  R2.d[0] = {c1buf, al_cce, sl_cce, CONC_N};
  R2.d[1] = {c2buf, al_ice, sl_ice, CONC_N};
  rowdots<<<dim3(16, 2), 256, 0, stream>>>(R2);

  // 8) conc_fused = conc_x + e1 + e2 (fused dual GAT on cc graph)
  gat_agg_dual<<<(CONC_N + 3) / 4, 256, 0, stream>>>(
      offs0, srcs0, sl_cce, sr_cce, c1buf, sl_ice, sr_ice, c2buf,
      conc_x, out_conc, CONC_N);

  // 9) item fusion: i1 then item_fused = item_x + i1 + i2
  gat_agg<<<(ITEM_N + 3) / 4, 256, 0, stream>>>(offs2, srcs2, sl_ci, sr_ci,
                                                concWci, nullptr, nullptr, i1buf, ITEM_N);
  gat_agg<<<(ITEM_N + 3) / 4, 256, 0, stream>>>(offs3, srcs3, sl_si, sr_si,
                                                stuWsi, item_x, i1buf, out_item, ITEM_N);

  // 10) student fusion: stu_fused = stu_raw_x + s1
  gat_agg<<<(STU_N + 3) / 4, 256, 0, stream>>>(offs4, srcs4, sl_is, sr_is,
                                               itemWis, stu_raw_x, nullptr, out_stu, STU_N);
}

// Round 2
// 726.093 us; speedup vs baseline: 6.6614x; 6.6614x over previous
//
#include <hip/hip_runtime.h>

#define CONC_N 2000
#define ITEM_N 20000
#define STU_N  50000
#define NE_CC  40000
#define NE_IC  80000
#define NE_SI  1000000

// ---------------- misc small kernels ----------------

__global__ void zero_ints(int* __restrict__ p, int n) {
  int i = blockIdx.x * blockDim.x + threadIdx.x;
  if (i < n) p[i] = 0;
}

// v[k] = sum_j W[j*128+k] * a[j]   (projected attention vector W^T a)
struct ProjDesc { const float* W; const float* a; float* out; };
struct ProjDescs { ProjDesc d[10]; };
__global__ void proj_vecs(ProjDescs P) {
  ProjDesc d = P.d[blockIdx.x];
  int k = threadIdx.x;  // 128 threads
  float acc = 0.f;
  for (int j = 0; j < 128; ++j) acc += d.W[j * 128 + k] * d.a[j];
  d.out[k] = acc;
}

// out[r] = dot(x[r,:], v)  -- wave per row
struct RowDotDesc { const float* x; const float* v; float* out; int n; };
struct RowDotDescs { RowDotDesc d[12]; };
__global__ void rowdots(RowDotDescs P) {
  RowDotDesc d = P.d[blockIdx.y];
  int lane = threadIdx.x & 63;
  int wid = (blockIdx.x * blockDim.x + threadIdx.x) >> 6;
  int nw = (gridDim.x * blockDim.x) >> 6;
  float v0 = d.v[lane], v1 = d.v[64 + lane];
  for (int r = wid; r < d.n; r += nw) {
    float a = d.x[r * 128 + lane] * v0 + d.x[r * 128 + 64 + lane] * v1;
    #pragma unroll
    for (int o = 32; o; o >>= 1) a += __shfl_xor(a, o);
    if (lane == 0) d.out[r] = a;
  }
}

// ---------------- CSR build ----------------

struct GraphDesc {
  const int* dst; const int* src;
  int* cnt; int* offs; int* cur; int* srcs;
  int E; int n;
};
struct GraphDescs { GraphDesc g[5]; };

__global__ void hist5(GraphDescs G) {
  GraphDesc g = G.g[blockIdx.y];
  for (int e = blockIdx.x * blockDim.x + threadIdx.x; e < g.E;
       e += gridDim.x * blockDim.x)
    atomicAdd(&g.cnt[g.dst[e]], 1);
}

__global__ __launch_bounds__(1024) void scan5(GraphDescs G) {
  GraphDesc g = G.g[blockIdx.x];
  __shared__ int wsum[16];
  __shared__ int ctot;
  int tid = threadIdx.x, lane = tid & 63, wv = tid >> 6;
  int run = 0;
  for (int base = 0; base < g.n; base += 1024) {
    int i = base + tid;
    int v = (i < g.n) ? g.cnt[i] : 0;
    int incl = v;
    #pragma unroll
    for (int o = 1; o < 64; o <<= 1) {
      int y = __shfl_up(incl, o);
      if (lane >= o) incl += y;
    }
    if (lane == 63) wsum[wv] = incl;
    __syncthreads();
    if (tid == 0) {
      int a = 0;
      #pragma unroll
      for (int w = 0; w < 16; ++w) { int t = wsum[w]; wsum[w] = a; a += t; }
      ctot = a;
    }
    __syncthreads();
    int excl = run + wsum[wv] + incl - v;
    if (i < g.n) { g.offs[i] = excl; g.cur[i] = excl; }
    run += ctot;
    __syncthreads();
  }
  if (tid == 0) g.offs[g.n] = run;
}

__global__ void fill5(GraphDescs G) {
  GraphDesc g = G.g[blockIdx.y];
  for (int e = blockIdx.x * blockDim.x + threadIdx.x; e < g.E;
       e += gridDim.x * blockDim.x) {
    int pos = atomicAdd(&g.cur[g.dst[e]], 1);
    g.srcs[pos] = g.src[e];
  }
}

// ---------------- GEMM: Y[n,128] = X[n,128] @ W[128,128]^T ----------------
// 64x128 block tile, 256 threads, 8x4 register tile per thread, BK=32.
// LDS transposed tiles: Xt[kk][row] (pad 68), Wt[kk][c] (pad 132) so the
// inner loop is 3 conflict-free ds_read_b128 per k-step feeding 32 FMAs.

__global__ __launch_bounds__(256, 2) void gemm128(const float* __restrict__ X,
                                                  const float* __restrict__ W,
                                                  float* __restrict__ Y, int n) {
  __shared__ float Xt[32 * 68];    // [kk][row], rows 0..63, pad to 68
  __shared__ float Wt[32 * 132];   // [kk][c],  c 0..127,  pad to 132
  int tid = threadIdx.x;
  int cg = tid & 31;               // cols cg*4 .. cg*4+3
  int rg = tid >> 5;               // rows rg*8 .. rg*8+7  (0..7)
  int rowbase = blockIdx.x * 64;
  float acc[8][4];
  #pragma unroll
  for (int i = 0; i < 8; ++i)
    #pragma unroll
    for (int j = 0; j < 4; ++j) acc[i][j] = 0.f;

  for (int kc = 0; kc < 4; ++kc) {
    int k0 = kc * 32;
    // stage X: 64 rows x 32 kk = 512 float4 slots, 2 per thread
    #pragma unroll
    for (int i = 0; i < 2; ++i) {
      int s = tid + i * 256;
      int row = s >> 3, kk4 = s & 7;
      int gr = rowbase + row;
      float4 xv = make_float4(0.f, 0.f, 0.f, 0.f);
      if (gr < n) xv = *(const float4*)&X[gr * 128 + k0 + kk4 * 4];
      Xt[(kk4 * 4 + 0) * 68 + row] = xv.x;
      Xt[(kk4 * 4 + 1) * 68 + row] = xv.y;
      Xt[(kk4 * 4 + 2) * 68 + row] = xv.z;
      Xt[(kk4 * 4 + 3) * 68 + row] = xv.w;
    }
    // stage W: 128 c x 32 kk = 1024 float4 slots, 4 per thread
    #pragma unroll
    for (int i = 0; i < 4; ++i) {
      int s = tid + i * 256;
      int c = s >> 3, kk4 = s & 7;
      float4 wv = *(const float4*)&W[c * 128 + k0 + kk4 * 4];
      Wt[(kk4 * 4 + 0) * 132 + c] = wv.x;
      Wt[(kk4 * 4 + 1) * 132 + c] = wv.y;
      Wt[(kk4 * 4 + 2) * 132 + c] = wv.z;
      Wt[(kk4 * 4 + 3) * 132 + c] = wv.w;
    }
    __syncthreads();
    #pragma unroll 4
    for (int kk = 0; kk < 32; ++kk) {
      float4 x0 = *(const float4*)&Xt[kk * 68 + rg * 8];
      float4 x1 = *(const float4*)&Xt[kk * 68 + rg * 8 + 4];
      float4 wv = *(const float4*)&Wt[kk * 132 + cg * 4];
      #pragma unroll
      for (int j = 0; j < 4; ++j) {
        float w = (j == 0) ? wv.x : (j == 1) ? wv.y : (j == 2) ? wv.z : wv.w;
        acc[0][j] += x0.x * w;
        acc[1][j] += x0.y * w;
        acc[2][j] += x0.z * w;
        acc[3][j] += x0.w * w;
        acc[4][j] += x1.x * w;
        acc[5][j] += x1.y * w;
        acc[6][j] += x1.z * w;
        acc[7][j] += x1.w * w;
      }
    }
    __syncthreads();
  }
  #pragma unroll
  for (int i = 0; i < 8; ++i) {
    int gr = rowbase + rg * 8 + i;
    if (gr < n) {
      float4 o4;
      o4.x = acc[i][0]; o4.y = acc[i][1]; o4.z = acc[i][2]; o4.w = acc[i][3];
      *(float4*)&Y[gr * 128 + cg * 4] = o4;
    }
  }
}

// ---------------- GAT aggregation (wave per target) ----------------

__global__ void gat_agg(const int* __restrict__ offs, const int* __restrict__ srcs,
                        const float* __restrict__ sl, const float* __restrict__ sr,
                        const float* __restrict__ xl,
                        const float* __restrict__ base0, const float* __restrict__ base1,
                        float* __restrict__ out, int n_tgt) {
  int t = (blockIdx.x * blockDim.x + threadIdx.x) >> 6;
  if (t >= n_tgt) return;
  int lane = threadIdx.x & 63;
  int sbeg = offs[t], send = offs[t + 1];
  float srt = sr[t];
  float m = -1e30f;
  for (int i = sbeg + lane; i < send; i += 64) {
    float e = sl[srcs[i]] + srt;
    e = e > 0.f ? e : 0.2f * e;
    m = fmaxf(m, e);
  }
  #pragma unroll
  for (int o = 32; o; o >>= 1) m = fmaxf(m, __shfl_xor(m, o));
  float se = 0.f;
  for (int i = sbeg + lane; i < send; i += 64) {
    float e = sl[srcs[i]] + srt;
    e = e > 0.f ? e : 0.2f * e;
    se += __expf(e - m);
  }
  #pragma unroll
  for (int o = 32; o; o >>= 1) se += __shfl_xor(se, o);
  float inv = 1.f / (se + 1e-16f);
  float ax = 0.f, ay = 0.f;
  for (int i0 = sbeg; i0 < send; i0 += 64) {
    int cnt = min(64, send - i0);
    int s = 0; float wgt = 0.f;
    if (lane < cnt) {
      s = srcs[i0 + lane];
      float e = sl[s] + srt;
      e = e > 0.f ? e : 0.2f * e;
      wgt = __expf(e - m) * inv;
    }
    for (int j = 0; j < cnt; ++j) {
      int sj = __shfl(s, j);
      float wj = __shfl(wgt, j);
      const float2 v = *(const float2*)&xl[sj * 128 + lane * 2];
      ax += wj * v.x; ay += wj * v.y;
    }
  }
  if (base0) { const float2 b = *(const float2*)&base0[t * 128 + lane * 2]; ax += b.x; ay += b.y; }
  if (base1) { const float2 b = *(const float2*)&base1[t * 128 + lane * 2]; ax += b.x; ay += b.y; }
  float2 o2; o2.x = ax; o2.y = ay;
  *(float2*)&out[t * 128 + lane * 2] = o2;
}

// e1 + e2 fused (both on the cc graph), writes conc_fused = base + r1 + r2
__global__ void gat_agg_dual(const int* __restrict__ offs, const int* __restrict__ srcs,
                             const float* __restrict__ sl1, const float* __restrict__ sr1,
                             const float* __restrict__ xl1,
                             const float* __restrict__ sl2, const float* __restrict__ sr2,
                             const float* __restrict__ xl2,
                             const float* __restrict__ base,
                             float* __restrict__ out, int n_tgt) {
  int t = (blockIdx.x * blockDim.x + threadIdx.x) >> 6;
  if (t >= n_tgt) return;
  int lane = threadIdx.x & 63;
  int sbeg = offs[t], send = offs[t + 1];
  float srt1 = sr1[t], srt2 = sr2[t];
  float m1 = -1e30f, m2 = -1e30f;
  for (int i = sbeg + lane; i < send; i += 64) {
    int s = srcs[i];
    float e1 = sl1[s] + srt1; e1 = e1 > 0.f ? e1 : 0.2f * e1;
    float e2 = sl2[s] + srt2; e2 = e2 > 0.f ? e2 : 0.2f * e2;
    m1 = fmaxf(m1, e1); m2 = fmaxf(m2, e2);
  }
  #pragma unroll
  for (int o = 32; o; o >>= 1) {
    m1 = fmaxf(m1, __shfl_xor(m1, o));
    m2 = fmaxf(m2, __shfl_xor(m2, o));
  }
  float se1 = 0.f, se2 = 0.f;
  for (int i = sbeg + lane; i < send; i += 64) {
    int s = srcs[i];
    float e1 = sl1[s] + srt1; e1 = e1 > 0.f ? e1 : 0.2f * e1;
    float e2 = sl2[s] + srt2; e2 = e2 > 0.f ? e2 : 0.2f * e2;
    se1 += __expf(e1 - m1); se2 += __expf(e2 - m2);
  }
  #pragma unroll
  for (int o = 32; o; o >>= 1) {
    se1 += __shfl_xor(se1, o);
    se2 += __shfl_xor(se2, o);
  }
  float inv1 = 1.f / (se1 + 1e-16f), inv2 = 1.f / (se2 + 1e-16f);
  float ax = 0.f, ay = 0.f;
  for (int i0 = sbeg; i0 < send; i0 += 64) {
    int cnt = min(64, send - i0);
    int s = 0; float w1 = 0.f, w2 = 0.f;
    if (lane < cnt) {
      s = srcs[i0 + lane];
      float e1 = sl1[s] + srt1; e1 = e1 > 0.f ? e1 : 0.2f * e1;
      float e2 = sl2[s] + srt2; e2 = e2 > 0.f ? e2 : 0.2f * e2;
      w1 = __expf(e1 - m1) * inv1;
      w2 = __expf(e2 - m2) * inv2;
    }
    for (int j = 0; j < cnt; ++j) {
      int sj = __shfl(s, j);
      float wj1 = __shfl(w1, j);
      float wj2 = __shfl(w2, j);
      const float2 v1 = *(const float2*)&xl1[sj * 128 + lane * 2];
      const float2 v2 = *(const float2*)&xl2[sj * 128 + lane * 2];
      ax += wj1 * v1.x + wj2 * v2.x;
      ay += wj1 * v1.y + wj2 * v2.y;
    }
  }
  const float2 b = *(const float2*)&base[t * 128 + lane * 2];
  float2 o2; o2.x = ax + b.x; o2.y = ay + b.y;
  *(float2*)&out[t * 128 + lane * 2] = o2;
}

// ---------------- launch ----------------

extern "C" void kernel_launch(void* const* d_in, const int* in_sizes, int n_in,
                              void* d_out, int out_size, void* d_ws, size_t ws_size,
                              hipStream_t stream) {
  const float* stu_x     = (const float*)d_in[0];
  const float* item_x    = (const float*)d_in[1];
  const float* conc_x    = (const float*)d_in[2];
  const float* stu_raw_x = (const float*)d_in[3];
  const float* W_cc  = (const float*)d_in[4];
  const float* al_cc = (const float*)d_in[5];
  const float* ar_cc = (const float*)d_in[6];
  const float* W_ic  = (const float*)d_in[7];
  const float* al_ic = (const float*)d_in[8];
  const float* ar_ic = (const float*)d_in[9];
  const float* al_cce = (const float*)d_in[10];
  const float* ar_cce = (const float*)d_in[11];
  const float* al_ice = (const float*)d_in[12];
  const float* ar_ice = (const float*)d_in[13];
  const float* W_ci  = (const float*)d_in[14];
  const float* al_ci = (const float*)d_in[15];
  const float* ar_ci = (const float*)d_in[16];
  const float* W_si  = (const float*)d_in[17];
  const float* al_si = (const float*)d_in[18];
  const float* ar_si = (const float*)d_in[19];
  const float* W_is  = (const float*)d_in[22];
  const float* al_is = (const float*)d_in[23];
  const float* ar_is = (const float*)d_in[24];
  const int* cc_src  = (const int*)d_in[25];
  const int* cc_dst  = (const int*)d_in[26];
  const int* ic_item = (const int*)d_in[27];
  const int* ic_conc = (const int*)d_in[28];
  const int* si_stu  = (const int*)d_in[29];
  const int* si_item = (const int*)d_in[30];

  char* wsb = (char*)d_ws;
  size_t off = 0;
  auto alloc = [&](size_t bytes) -> void* {
    void* p = wsb + off;
    off = (off + bytes + 255) & ~(size_t)255;
    return p;
  };

  float* concWcc = (float*)alloc((size_t)CONC_N * 128 * 4);
  float* itemWic = (float*)alloc((size_t)ITEM_N * 128 * 4);
  float* concWci = (float*)alloc((size_t)CONC_N * 128 * 4);
  float* stuWsi  = (float*)alloc((size_t)STU_N  * 128 * 4);
  float* itemWis = (float*)alloc((size_t)ITEM_N * 128 * 4);
  float* c1buf   = (float*)alloc((size_t)CONC_N * 128 * 4);
  float* c2buf   = (float*)alloc((size_t)CONC_N * 128 * 4);
  float* i1buf   = (float*)alloc((size_t)ITEM_N * 128 * 4);
  float* vecs    = (float*)alloc(10 * 128 * 4);   // projected att vectors
  float* sl_cc  = (float*)alloc(CONC_N * 4);
  float* sr_cc  = (float*)alloc(CONC_N * 4);
  float* sl_ic  = (float*)alloc(ITEM_N * 4);
  float* sr_ic  = (float*)alloc(CONC_N * 4);
  float* sl_ci  = (float*)alloc(CONC_N * 4);
  float* sr_ci  = (float*)alloc(ITEM_N * 4);
  float* sl_si  = (float*)alloc(STU_N * 4);
  float* sr_si  = (float*)alloc(ITEM_N * 4);
  float* sl_is  = (float*)alloc(ITEM_N * 4);
  float* sr_is  = (float*)alloc(STU_N * 4);
  float* sl_cce = (float*)alloc(CONC_N * 4);
  float* sr_cce = (float*)alloc(CONC_N * 4);
  float* sl_ice = (float*)alloc(CONC_N * 4);
  float* sr_ice = (float*)alloc(CONC_N * 4);

  // CSR buffers: 5 graphs (cnt arrays contiguous for one zero pass)
  const int ncnt_tot = CONC_N + CONC_N + ITEM_N + ITEM_N + STU_N;  // 94000
  int* cnt_all = (int*)alloc((size_t)ncnt_tot * 4);
  int* cnt0 = cnt_all;
  int* cnt1 = cnt0 + CONC_N;
  int* cnt2 = cnt1 + CONC_N;
  int* cnt3 = cnt2 + ITEM_N;
  int* cnt4 = cnt3 + ITEM_N;
  int* offs0 = (int*)alloc((CONC_N + 1) * 4);
  int* offs1 = (int*)alloc((CONC_N + 1) * 4);
  int* offs2 = (int*)alloc((ITEM_N + 1) * 4);
  int* offs3 = (int*)alloc((ITEM_N + 1) * 4);
  int* offs4 = (int*)alloc((STU_N + 1) * 4);
  int* cur0 = (int*)alloc(CONC_N * 4);
  int* cur1 = (int*)alloc(CONC_N * 4);
  int* cur2 = (int*)alloc(ITEM_N * 4);
  int* cur3 = (int*)alloc(ITEM_N * 4);
  int* cur4 = (int*)alloc(STU_N * 4);
  int* srcs0 = (int*)alloc((size_t)NE_CC * 4);
  int* srcs1 = (int*)alloc((size_t)NE_IC * 4);
  int* srcs2 = (int*)alloc((size_t)NE_IC * 4);
  int* srcs3 = (int*)alloc((size_t)NE_SI * 4);
  int* srcs4 = (int*)alloc((size_t)NE_SI * 4);

  float* out = (float*)d_out;
  float* out_conc = out;
  float* out_item = out + (size_t)CONC_N * 128;
  float* out_stu  = out + (size_t)(CONC_N + ITEM_N) * 128;

  // 1) zero counters
  zero_ints<<<(ncnt_tot + 255) / 256, 256, 0, stream>>>(cnt_all, ncnt_tot);

  // 2) projected attention vectors
  ProjDescs P;
  P.d[0] = {W_cc, al_cc, vecs + 0 * 128};
  P.d[1] = {W_cc, ar_cc, vecs + 1 * 128};
  P.d[2] = {W_ic, al_ic, vecs + 2 * 128};
  P.d[3] = {W_ic, ar_ic, vecs + 3 * 128};
  P.d[4] = {W_ci, al_ci, vecs + 4 * 128};
  P.d[5] = {W_ci, ar_ci, vecs + 5 * 128};
  P.d[6] = {W_si, al_si, vecs + 6 * 128};
  P.d[7] = {W_si, ar_si, vecs + 7 * 128};
  P.d[8] = {W_is, al_is, vecs + 8 * 128};
  P.d[9] = {W_is, ar_is, vecs + 9 * 128};
  proj_vecs<<<10, 128, 0, stream>>>(P);

  // 3) CSR build: graphs {cc, icC, icI, siI, siS}
  GraphDescs G;
  G.g[0] = {cc_dst,  cc_src,  cnt0, offs0, cur0, srcs0, NE_CC, CONC_N};
  G.g[1] = {ic_conc, ic_item, cnt1, offs1, cur1, srcs1, NE_IC, CONC_N};
  G.g[2] = {ic_item, ic_conc, cnt2, offs2, cur2, srcs2, NE_IC, ITEM_N};
  G.g[3] = {si_item, si_stu,  cnt3, offs3, cur3, srcs3, NE_SI, ITEM_N};
  G.g[4] = {si_stu,  si_item, cnt4, offs4, cur4, srcs4, NE_SI, STU_N};
  hist5<<<dim3(1024, 5), 256, 0, stream>>>(G);
  scan5<<<5, 1024, 0, stream>>>(G);
  fill5<<<dim3(1024, 5), 256, 0, stream>>>(G);

  // 4) linear transforms (only the xl's we need to materialize)
  gemm128<<<(CONC_N + 63) / 64, 256, 0, stream>>>(conc_x, W_cc, concWcc, CONC_N);
  gemm128<<<(ITEM_N + 63) / 64, 256, 0, stream>>>(item_x, W_ic, itemWic, ITEM_N);
  gemm128<<<(CONC_N + 63) / 64, 256, 0, stream>>>(conc_x, W_ci, concWci, CONC_N);
  gemm128<<<(STU_N  + 63) / 64, 256, 0, stream>>>(stu_x,  W_si, stuWsi,  STU_N);
  gemm128<<<(ITEM_N + 63) / 64, 256, 0, stream>>>(item_x, W_is, itemWis, ITEM_N);

  // 5) per-node attention scores, batch 1
  RowDotDescs R1;
  R1.d[0]  = {conc_x,    vecs + 0 * 128, sl_cc, CONC_N};
  R1.d[1]  = {conc_x,    vecs + 1 * 128, sr_cc, CONC_N};
  R1.d[2]  = {item_x,    vecs + 2 * 128, sl_ic, ITEM_N};
  R1.d[3]  = {conc_x,    vecs + 3 * 128, sr_ic, CONC_N};
  R1.d[4]  = {conc_x,    vecs + 4 * 128, sl_ci, CONC_N};
  R1.d[5]  = {item_x,    vecs + 5 * 128, sr_ci, ITEM_N};
  R1.d[6]  = {stu_x,     vecs + 6 * 128, sl_si, STU_N};
  R1.d[7]  = {item_x,    vecs + 7 * 128, sr_si, ITEM_N};
  R1.d[8]  = {item_x,    vecs + 8 * 128, sl_is, ITEM_N};
  R1.d[9]  = {stu_raw_x, vecs + 9 * 128, sr_is, STU_N};
  R1.d[10] = {conc_x,    ar_cce,         sr_cce, CONC_N};
  R1.d[11] = {conc_x,    ar_ice,         sr_ice, CONC_N};
  rowdots<<<dim3(128, 12), 256, 0, stream>>>(R1);

  // 6) c1, c2 (inter GATs on concept targets)
  gat_agg<<<(CONC_N + 3) / 4, 256, 0, stream>>>(offs0, srcs0, sl_cc, sr_cc,
                                                concWcc, nullptr, nullptr, c1buf, CONC_N);
  gat_agg<<<(CONC_N + 3) / 4, 256, 0, stream>>>(offs1, srcs1, sl_ic, sr_ic,
                                                itemWic, nullptr, nullptr, c2buf, CONC_N);

  // 7) scores that depend on c1/c2
  RowDotDescs R2;
  R2.d[0] = {c1buf, al_cce, sl_cce, CONC_N};
  R2.d[1] = {c2buf, al_ice, sl_ice, CONC_N};
  rowdots<<<dim3(16, 2), 256, 0, stream>>>(R2);

  // 8) conc_fused = conc_x + e1 + e2 (fused dual GAT on cc graph)
  gat_agg_dual<<<(CONC_N + 3) / 4, 256, 0, stream>>>(
      offs0, srcs0, sl_cce, sr_cce, c1buf, sl_ice, sr_ice, c2buf,
      conc_x, out_conc, CONC_N);

  // 9) item fusion: i1 then item_fused = item_x + i1 + i2
  gat_agg<<<(ITEM_N + 3) / 4, 256, 0, stream>>>(offs2, srcs2, sl_ci, sr_ci,
                                                concWci, nullptr, nullptr, i1buf, ITEM_N);
  gat_agg<<<(ITEM_N + 3) / 4, 256, 0, stream>>>(offs3, srcs3, sl_si, sr_si,
                                                stuWsi, item_x, i1buf, out_item, ITEM_N);

  // 10) student fusion: stu_fused = stu_raw_x + s1
  gat_agg<<<(STU_N + 3) / 4, 256, 0, stream>>>(offs4, srcs4, sl_is, sr_is,
                                               itemWis, stu_raw_x, nullptr, out_stu, STU_N);
}

// Round 3
// 501.279 us; speedup vs baseline: 9.6489x; 1.4485x over previous
//
#include <hip/hip_runtime.h>

#define CONC_N 2000
#define ITEM_N 20000
#define STU_N  50000
#define NE_CC  40000
#define NE_IC  80000
#define NE_SI  1000000
#define TBUCK  382   // 63+63+79+79+98

// ---------------- misc small kernels ----------------

__global__ void zero_ints(int* __restrict__ p, int n) {
  int i = blockIdx.x * blockDim.x + threadIdx.x;
  if (i < n) p[i] = 0;
}

// v[k] = sum_j W[j*128+k] * a[j]   (projected attention vector W^T a)
struct ProjDesc { const float* W; const float* a; float* out; };
struct ProjDescs { ProjDesc d[10]; };
__global__ void proj_vecs(ProjDescs P) {
  ProjDesc d = P.d[blockIdx.x];
  int k = threadIdx.x;  // 128 threads
  float acc = 0.f;
  for (int j = 0; j < 128; ++j) acc += d.W[j * 128 + k] * d.a[j];
  d.out[k] = acc;
}

// multi-vector row dots: out[j][r] = dot(x[r,:], v[j]) for j < nv
struct MDot { const float* x; const float* v[6]; float* o[6]; int n; int nv; };
struct MDots { MDot d[4]; };
__global__ void mdots(MDots P) {
  MDot d = P.d[blockIdx.y];
  int lane = threadIdx.x & 63;
  int wid = (blockIdx.x * blockDim.x + threadIdx.x) >> 6;
  int nw = (gridDim.x * blockDim.x) >> 6;
  float va[6], vb[6];
  for (int j = 0; j < d.nv; ++j) { va[j] = d.v[j][lane]; vb[j] = d.v[j][64 + lane]; }
  for (int r = wid; r < d.n; r += nw) {
    float x0 = d.x[r * 128 + lane], x1 = d.x[r * 128 + 64 + lane];
    float acc[6];
    for (int j = 0; j < d.nv; ++j) {
      float a = x0 * va[j] + x1 * vb[j];
      #pragma unroll
      for (int o = 32; o; o >>= 1) a += __shfl_xor(a, o);
      acc[j] = a;
    }
    if (lane == 0)
      for (int j = 0; j < d.nv; ++j) d.o[j][r] = acc[j];
  }
}

// ---------------- CSR build via bucketed counting sort ----------------
// bucket = dst >> shift (dpb = 1<<shift <= 512); key = (dst_low<<16)|src.

struct CsrG {
  const int* dst; const int* src;
  unsigned* keys; int* srcs; int* offs;
  int E, n, shift, nbuck, tb, sb;   // tb: bucket offset; sb: tb + graph_index
};
struct CsrGs { CsrG g[5]; };

__global__ void csr_count(CsrGs G, int* __restrict__ bcnt) {
  CsrG g = G.g[blockIdx.y];
  __shared__ int lcnt[128];
  int tid = threadIdx.x;
  if (tid < 128) lcnt[tid] = 0;
  __syncthreads();
  for (int e = blockIdx.x * blockDim.x + tid; e < g.E; e += gridDim.x * blockDim.x)
    atomicAdd(&lcnt[g.dst[e] >> g.shift], 1);
  __syncthreads();
  if (tid < g.nbuck && lcnt[tid] > 0) atomicAdd(&bcnt[g.tb + tid], lcnt[tid]);
}

__global__ __launch_bounds__(512) void csr_scan(CsrGs G, const int* __restrict__ bcnt,
                                                int* __restrict__ cur, int* __restrict__ bases) {
  __shared__ int lc[TBUCK];
  __shared__ int lb[TBUCK + 5];
  int tid = threadIdx.x;
  if (tid < TBUCK) lc[tid] = bcnt[tid];
  __syncthreads();
  if (tid == 0) {
    for (int gi = 0; gi < 5; ++gi) {
      CsrG g = G.g[gi];
      int run = 0;
      for (int b = 0; b < g.nbuck; ++b) { lb[g.sb + b] = run; run += lc[g.tb + b]; }
      lb[g.sb + g.nbuck] = run;
    }
  }
  __syncthreads();
  if (tid < TBUCK + 5) bases[tid] = lb[tid];
  if (tid < TBUCK) {
    int gi = 0;
    for (int k = 1; k < 5; ++k) if (tid >= G.g[k].tb) gi = k;
    cur[tid] = lb[tid + gi];
  }
  if (tid < 5) G.g[tid].offs[G.g[tid].n] = G.g[tid].E;
}

__global__ __launch_bounds__(256) void csr_partition(CsrGs G, int* __restrict__ cur) {
  CsrG g = G.g[blockIdx.y];
  __shared__ unsigned ck[4096];
  __shared__ unsigned char cb[4096];
  __shared__ int lcnt[128], lcur[128];
  int tid = threadIdx.x;
  unsigned dmask = (1u << g.shift) - 1;
  for (int c0 = blockIdx.x * 4096; c0 < g.E; c0 += gridDim.x * 4096) {
    if (tid < 128) lcnt[tid] = 0;
    __syncthreads();
    #pragma unroll
    for (int i = 0; i < 16; ++i) {
      int e = c0 + i * 256 + tid;
      if (e < g.E) {
        int d = g.dst[e], s = g.src[e];
        int b = d >> g.shift;
        ck[i * 256 + tid] = ((unsigned)(d & dmask) << 16) | (unsigned)s;
        cb[i * 256 + tid] = (unsigned char)b;
        atomicAdd(&lcnt[b], 1);
      } else cb[i * 256 + tid] = 255;
    }
    __syncthreads();
    if (tid < g.nbuck && lcnt[tid] > 0) lcur[tid] = atomicAdd(&cur[g.tb + tid], lcnt[tid]);
    __syncthreads();
    #pragma unroll
    for (int i = 0; i < 16; ++i) {
      int b = cb[i * 256 + tid];
      if (b != 255) {
        int pos = atomicAdd(&lcur[b], 1);
        g.keys[pos] = ck[i * 256 + tid];
      }
    }
    __syncthreads();
  }
}

__global__ __launch_bounds__(256) void csr_build(CsrGs G, const int* __restrict__ bases) {
  int bid = blockIdx.x;
  int gi = 0;
  for (int k = 1; k < 5; ++k) if (bid >= G.g[k].tb) gi = k;
  CsrG g = G.g[gi];
  int b = bid - g.tb;
  int base = bases[g.sb + b];
  int cnt = bases[g.sb + b + 1] - base;
  if (cnt > 16384) cnt = 16384;  // safety clamp (never expected)

  __shared__ unsigned lkeys[16384];
  __shared__ int lh[512], lex[512], lcu[512], wsum[4];
  int tid = threadIdx.x;
  lh[tid] = 0; lh[tid + 256] = 0;
  __syncthreads();
  for (int j = tid; j < cnt; j += 256) {
    unsigned k = g.keys[base + j];
    lkeys[j] = k;
    atomicAdd(&lh[k >> 16], 1);
  }
  __syncthreads();
  // exclusive scan of lh[0..511] -> lex, lcu
  int a0 = lh[2 * tid], a1 = lh[2 * tid + 1];
  int pair = a0 + a1;
  int lane = tid & 63, wv = tid >> 6;
  int incl = pair;
  #pragma unroll
  for (int o = 1; o < 64; o <<= 1) {
    int y = __shfl_up(incl, o);
    if (lane >= o) incl += y;
  }
  if (lane == 63) wsum[wv] = incl;
  __syncthreads();
  if (tid == 0) {
    int s = 0;
    #pragma unroll
    for (int w = 0; w < 4; ++w) { int t = wsum[w]; wsum[w] = s; s += t; }
  }
  __syncthreads();
  int ep = wsum[wv] + incl - pair;
  lex[2 * tid] = ep;       lex[2 * tid + 1] = ep + a0;
  lcu[2 * tid] = ep;       lcu[2 * tid + 1] = ep + a0;
  __syncthreads();
  int dst0 = b << g.shift;
  int ndst = min(1 << g.shift, g.n - dst0);
  for (int dl = tid; dl < ndst; dl += 256) g.offs[dst0 + dl] = base + lex[dl];
  for (int j = tid; j < cnt; j += 256) {
    unsigned k = lkeys[j];
    int dl = k >> 16;
    int pos = atomicAdd(&lcu[dl], 1);
    g.srcs[base + pos] = (int)(k & 0xFFFFu);
  }
}

// ---------------- GEMM: Y[n,128] = X[n,128] @ W[128,128]^T ----------------

__global__ __launch_bounds__(256, 2) void gemm128(const float* __restrict__ X,
                                                  const float* __restrict__ W,
                                                  float* __restrict__ Y, int n) {
  __shared__ float Xt[32 * 68];    // [kk][row], rows 0..63, pad to 68
  __shared__ float Wt[32 * 132];   // [kk][c],  c 0..127,  pad to 132
  int tid = threadIdx.x;
  int cg = tid & 31;               // cols cg*4 .. cg*4+3
  int rg = tid >> 5;               // rows rg*8 .. rg*8+7
  int rowbase = blockIdx.x * 64;
  float acc[8][4];
  #pragma unroll
  for (int i = 0; i < 8; ++i)
    #pragma unroll
    for (int j = 0; j < 4; ++j) acc[i][j] = 0.f;

  for (int kc = 0; kc < 4; ++kc) {
    int k0 = kc * 32;
    #pragma unroll
    for (int i = 0; i < 2; ++i) {
      int s = tid + i * 256;
      int row = s >> 3, kk4 = s & 7;
      int gr = rowbase + row;
      float4 xv = make_float4(0.f, 0.f, 0.f, 0.f);
      if (gr < n) xv = *(const float4*)&X[gr * 128 + k0 + kk4 * 4];
      Xt[(kk4 * 4 + 0) * 68 + row] = xv.x;
      Xt[(kk4 * 4 + 1) * 68 + row] = xv.y;
      Xt[(kk4 * 4 + 2) * 68 + row] = xv.z;
      Xt[(kk4 * 4 + 3) * 68 + row] = xv.w;
    }
    #pragma unroll
    for (int i = 0; i < 4; ++i) {
      int s = tid + i * 256;
      int c = s >> 3, kk4 = s & 7;
      float4 wv = *(const float4*)&W[c * 128 + k0 + kk4 * 4];
      Wt[(kk4 * 4 + 0) * 132 + c] = wv.x;
      Wt[(kk4 * 4 + 1) * 132 + c] = wv.y;
      Wt[(kk4 * 4 + 2) * 132 + c] = wv.z;
      Wt[(kk4 * 4 + 3) * 132 + c] = wv.w;
    }
    __syncthreads();
    #pragma unroll 4
    for (int kk = 0; kk < 32; ++kk) {
      float4 x0 = *(const float4*)&Xt[kk * 68 + rg * 8];
      float4 x1 = *(const float4*)&Xt[kk * 68 + rg * 8 + 4];
      float4 wv = *(const float4*)&Wt[kk * 132 + cg * 4];
      #pragma unroll
      for (int j = 0; j < 4; ++j) {
        float w = (j == 0) ? wv.x : (j == 1) ? wv.y : (j == 2) ? wv.z : wv.w;
        acc[0][j] += x0.x * w;
        acc[1][j] += x0.y * w;
        acc[2][j] += x0.z * w;
        acc[3][j] += x0.w * w;
        acc[4][j] += x1.x * w;
        acc[5][j] += x1.y * w;
        acc[6][j] += x1.z * w;
        acc[7][j] += x1.w * w;
      }
    }
    __syncthreads();
  }
  #pragma unroll
  for (int i = 0; i < 8; ++i) {
    int gr = rowbase + rg * 8 + i;
    if (gr < n) {
      float4 o4;
      o4.x = acc[i][0]; o4.y = acc[i][1]; o4.z = acc[i][2]; o4.w = acc[i][3];
      *(float4*)&Y[gr * 128 + cg * 4] = o4;
    }
  }
}

// ---------------- GAT aggregation (wave per target) ----------------

__global__ void gat_agg(const int* __restrict__ offs, const int* __restrict__ srcs,
                        const float* __restrict__ sl, const float* __restrict__ sr,
                        const float* __restrict__ xl,
                        const float* __restrict__ base0, const float* __restrict__ base1,
                        float* __restrict__ out, int n_tgt) {
  int t = (blockIdx.x * blockDim.x + threadIdx.x) >> 6;
  if (t >= n_tgt) return;
  int lane = threadIdx.x & 63;
  int sbeg = offs[t], send = offs[t + 1];
  float srt = sr[t];
  float m = -1e30f;
  for (int i = sbeg + lane; i < send; i += 64) {
    float e = sl[srcs[i]] + srt;
    e = e > 0.f ? e : 0.2f * e;
    m = fmaxf(m, e);
  }
  #pragma unroll
  for (int o = 32; o; o >>= 1) m = fmaxf(m, __shfl_xor(m, o));
  float se = 0.f;
  for (int i = sbeg + lane; i < send; i += 64) {
    float e = sl[srcs[i]] + srt;
    e = e > 0.f ? e : 0.2f * e;
    se += __expf(e - m);
  }
  #pragma unroll
  for (int o = 32; o; o >>= 1) se += __shfl_xor(se, o);
  float inv = 1.f / (se + 1e-16f);
  float ax = 0.f, ay = 0.f;
  for (int i0 = sbeg; i0 < send; i0 += 64) {
    int cnt = min(64, send - i0);
    int s = 0; float wgt = 0.f;
    if (lane < cnt) {
      s = srcs[i0 + lane];
      float e = sl[s] + srt;
      e = e > 0.f ? e : 0.2f * e;
      wgt = __expf(e - m) * inv;
    }
    for (int j = 0; j < cnt; ++j) {
      int sj = __shfl(s, j);
      float wj = __shfl(wgt, j);
      const float2 v = *(const float2*)&xl[sj * 128 + lane * 2];
      ax += wj * v.x; ay += wj * v.y;
    }
  }
  if (base0) { const float2 b = *(const float2*)&base0[t * 128 + lane * 2]; ax += b.x; ay += b.y; }
  if (base1) { const float2 b = *(const float2*)&base1[t * 128 + lane * 2]; ax += b.x; ay += b.y; }
  float2 o2; o2.x = ax; o2.y = ay;
  *(float2*)&out[t * 128 + lane * 2] = o2;
}

__global__ void gat_agg_dual(const int* __restrict__ offs, const int* __restrict__ srcs,
                             const float* __restrict__ sl1, const float* __restrict__ sr1,
                             const float* __restrict__ xl1,
                             const float* __restrict__ sl2, const float* __restrict__ sr2,
                             const float* __restrict__ xl2,
                             const float* __restrict__ base,
                             float* __restrict__ out, int n_tgt) {
  int t = (blockIdx.x * blockDim.x + threadIdx.x) >> 6;
  if (t >= n_tgt) return;
  int lane = threadIdx.x & 63;
  int sbeg = offs[t], send = offs[t + 1];
  float srt1 = sr1[t], srt2 = sr2[t];
  float m1 = -1e30f, m2 = -1e30f;
  for (int i = sbeg + lane; i < send; i += 64) {
    int s = srcs[i];
    float e1 = sl1[s] + srt1; e1 = e1 > 0.f ? e1 : 0.2f * e1;
    float e2 = sl2[s] + srt2; e2 = e2 > 0.f ? e2 : 0.2f * e2;
    m1 = fmaxf(m1, e1); m2 = fmaxf(m2, e2);
  }
  #pragma unroll
  for (int o = 32; o; o >>= 1) {
    m1 = fmaxf(m1, __shfl_xor(m1, o));
    m2 = fmaxf(m2, __shfl_xor(m2, o));
  }
  float se1 = 0.f, se2 = 0.f;
  for (int i = sbeg + lane; i < send; i += 64) {
    int s = srcs[i];
    float e1 = sl1[s] + srt1; e1 = e1 > 0.f ? e1 : 0.2f * e1;
    float e2 = sl2[s] + srt2; e2 = e2 > 0.f ? e2 : 0.2f * e2;
    se1 += __expf(e1 - m1); se2 += __expf(e2 - m2);
  }
  #pragma unroll
  for (int o = 32; o; o >>= 1) {
    se1 += __shfl_xor(se1, o);
    se2 += __shfl_xor(se2, o);
  }
  float inv1 = 1.f / (se1 + 1e-16f), inv2 = 1.f / (se2 + 1e-16f);
  float ax = 0.f, ay = 0.f;
  for (int i0 = sbeg; i0 < send; i0 += 64) {
    int cnt = min(64, send - i0);
    int s = 0; float w1 = 0.f, w2 = 0.f;
    if (lane < cnt) {
      s = srcs[i0 + lane];
      float e1 = sl1[s] + srt1; e1 = e1 > 0.f ? e1 : 0.2f * e1;
      float e2 = sl2[s] + srt2; e2 = e2 > 0.f ? e2 : 0.2f * e2;
      w1 = __expf(e1 - m1) * inv1;
      w2 = __expf(e2 - m2) * inv2;
    }
    for (int j = 0; j < cnt; ++j) {
      int sj = __shfl(s, j);
      float wj1 = __shfl(w1, j);
      float wj2 = __shfl(w2, j);
      const float2 v1 = *(const float2*)&xl1[sj * 128 + lane * 2];
      const float2 v2 = *(const float2*)&xl2[sj * 128 + lane * 2];
      ax += wj1 * v1.x + wj2 * v2.x;
      ay += wj1 * v1.y + wj2 * v2.y;
    }
  }
  const float2 b = *(const float2*)&base[t * 128 + lane * 2];
  float2 o2; o2.x = ax + b.x; o2.y = ay + b.y;
  *(float2*)&out[t * 128 + lane * 2] = o2;
}

// ---------------- launch ----------------

extern "C" void kernel_launch(void* const* d_in, const int* in_sizes, int n_in,
                              void* d_out, int out_size, void* d_ws, size_t ws_size,
                              hipStream_t stream) {
  const float* stu_x     = (const float*)d_in[0];
  const float* item_x    = (const float*)d_in[1];
  const float* conc_x    = (const float*)d_in[2];
  const float* stu_raw_x = (const float*)d_in[3];
  const float* W_cc  = (const float*)d_in[4];
  const float* al_cc = (const float*)d_in[5];
  const float* ar_cc = (const float*)d_in[6];
  const float* W_ic  = (const float*)d_in[7];
  const float* al_ic = (const float*)d_in[8];
  const float* ar_ic = (const float*)d_in[9];
  const float* al_cce = (const float*)d_in[10];
  const float* ar_cce = (const float*)d_in[11];
  const float* al_ice = (const float*)d_in[12];
  const float* ar_ice = (const float*)d_in[13];
  const float* W_ci  = (const float*)d_in[14];
  const float* al_ci = (const float*)d_in[15];
  const float* ar_ci = (const float*)d_in[16];
  const float* W_si  = (const float*)d_in[17];
  const float* al_si = (const float*)d_in[18];
  const float* ar_si = (const float*)d_in[19];
  const float* W_is  = (const float*)d_in[22];
  const float* al_is = (const float*)d_in[23];
  const float* ar_is = (const float*)d_in[24];
  const int* cc_src  = (const int*)d_in[25];
  const int* cc_dst  = (const int*)d_in[26];
  const int* ic_item = (const int*)d_in[27];
  const int* ic_conc = (const int*)d_in[28];
  const int* si_stu  = (const int*)d_in[29];
  const int* si_item = (const int*)d_in[30];

  char* wsb = (char*)d_ws;
  size_t off = 0;
  auto alloc = [&](size_t bytes) -> void* {
    void* p = wsb + off;
    off = (off + bytes + 255) & ~(size_t)255;
    return p;
  };

  float* concWcc = (float*)alloc((size_t)CONC_N * 128 * 4);
  float* itemWic = (float*)alloc((size_t)ITEM_N * 128 * 4);
  float* concWci = (float*)alloc((size_t)CONC_N * 128 * 4);
  float* stuWsi  = (float*)alloc((size_t)STU_N  * 128 * 4);
  float* itemWis = (float*)alloc((size_t)ITEM_N * 128 * 4);
  float* c1buf   = (float*)alloc((size_t)CONC_N * 128 * 4);
  float* c2buf   = (float*)alloc((size_t)CONC_N * 128 * 4);
  float* i1buf   = (float*)alloc((size_t)ITEM_N * 128 * 4);
  float* vecs    = (float*)alloc(10 * 128 * 4);
  float* sl_cc  = (float*)alloc(CONC_N * 4);
  float* sr_cc  = (float*)alloc(CONC_N * 4);
  float* sl_ic  = (float*)alloc(ITEM_N * 4);
  float* sr_ic  = (float*)alloc(CONC_N * 4);
  float* sl_ci  = (float*)alloc(CONC_N * 4);
  float* sr_ci  = (float*)alloc(ITEM_N * 4);
  float* sl_si  = (float*)alloc(STU_N * 4);
  float* sr_si  = (float*)alloc(ITEM_N * 4);
  float* sl_is  = (float*)alloc(ITEM_N * 4);
  float* sr_is  = (float*)alloc(STU_N * 4);
  float* sl_cce = (float*)alloc(CONC_N * 4);
  float* sr_cce = (float*)alloc(CONC_N * 4);
  float* sl_ice = (float*)alloc(CONC_N * 4);
  float* sr_ice = (float*)alloc(CONC_N * 4);

  // CSR buffers
  unsigned* keys0 = (unsigned*)alloc((size_t)NE_CC * 4);
  unsigned* keys1 = (unsigned*)alloc((size_t)NE_IC * 4);
  unsigned* keys2 = (unsigned*)alloc((size_t)NE_IC * 4);
  unsigned* keys3 = (unsigned*)alloc((size_t)NE_SI * 4);
  unsigned* keys4 = (unsigned*)alloc((size_t)NE_SI * 4);
  int* srcs0 = (int*)alloc((size_t)NE_CC * 4);
  int* srcs1 = (int*)alloc((size_t)NE_IC * 4);
  int* srcs2 = (int*)alloc((size_t)NE_IC * 4);
  int* srcs3 = (int*)alloc((size_t)NE_SI * 4);
  int* srcs4 = (int*)alloc((size_t)NE_SI * 4);
  int* offs0 = (int*)alloc((CONC_N + 1) * 4);
  int* offs1 = (int*)alloc((CONC_N + 1) * 4);
  int* offs2 = (int*)alloc((ITEM_N + 1) * 4);
  int* offs3 = (int*)alloc((ITEM_N + 1) * 4);
  int* offs4 = (int*)alloc((STU_N + 1) * 4);
  int* bcnt_all  = (int*)alloc(TBUCK * 4);
  int* cur_all   = (int*)alloc(TBUCK * 4);
  int* bases_all = (int*)alloc((TBUCK + 5) * 4);

  float* out = (float*)d_out;
  float* out_conc = out;
  float* out_item = out + (size_t)CONC_N * 128;
  float* out_stu  = out + (size_t)(CONC_N + ITEM_N) * 128;

  // graph table: {dst, src, keys, srcs, offs, E, n, shift, nbuck, tb, sb}
  CsrGs G;
  G.g[0] = {cc_dst,  cc_src,  keys0, srcs0, offs0, NE_CC, CONC_N, 5, 63,   0,   0};
  G.g[1] = {ic_conc, ic_item, keys1, srcs1, offs1, NE_IC, CONC_N, 5, 63,  63,  64};
  G.g[2] = {ic_item, ic_conc, keys2, srcs2, offs2, NE_IC, ITEM_N, 8, 79, 126, 128};
  G.g[3] = {si_item, si_stu,  keys3, srcs3, offs3, NE_SI, ITEM_N, 8, 79, 205, 208};
  G.g[4] = {si_stu,  si_item, keys4, srcs4, offs4, NE_SI, STU_N,  9, 98, 284, 288};

  // 1) zero bucket counters
  zero_ints<<<2, 256, 0, stream>>>(bcnt_all, TBUCK);

  // 2) projected attention vectors
  ProjDescs P;
  P.d[0] = {W_cc, al_cc, vecs + 0 * 128};
  P.d[1] = {W_cc, ar_cc, vecs + 1 * 128};
  P.d[2] = {W_ic, al_ic, vecs + 2 * 128};
  P.d[3] = {W_ic, ar_ic, vecs + 3 * 128};
  P.d[4] = {W_ci, al_ci, vecs + 4 * 128};
  P.d[5] = {W_ci, ar_ci, vecs + 5 * 128};
  P.d[6] = {W_si, al_si, vecs + 6 * 128};
  P.d[7] = {W_si, ar_si, vecs + 7 * 128};
  P.d[8] = {W_is, al_is, vecs + 8 * 128};
  P.d[9] = {W_is, ar_is, vecs + 9 * 128};
  proj_vecs<<<10, 128, 0, stream>>>(P);

  // 3) CSR build (bucketed counting sort)
  csr_count<<<dim3(128, 5), 256, 0, stream>>>(G, bcnt_all);
  csr_scan<<<1, 512, 0, stream>>>(G, bcnt_all, cur_all, bases_all);
  csr_partition<<<dim3(120, 5), 256, 0, stream>>>(G, cur_all);
  csr_build<<<TBUCK, 256, 0, stream>>>(G, bases_all);

  // 4) linear transforms
  gemm128<<<(CONC_N + 63) / 64, 256, 0, stream>>>(conc_x, W_cc, concWcc, CONC_N);
  gemm128<<<(ITEM_N + 63) / 64, 256, 0, stream>>>(item_x, W_ic, itemWic, ITEM_N);
  gemm128<<<(CONC_N + 63) / 64, 256, 0, stream>>>(conc_x, W_ci, concWci, CONC_N);
  gemm128<<<(STU_N  + 63) / 64, 256, 0, stream>>>(stu_x,  W_si, stuWsi,  STU_N);
  gemm128<<<(ITEM_N + 63) / 64, 256, 0, stream>>>(item_x, W_is, itemWis, ITEM_N);

  // 5) per-node attention scores (fused multi-dot per source array)
  MDots R1;
  R1.d[0] = {conc_x, {vecs + 0 * 128, vecs + 1 * 128, vecs + 3 * 128, vecs + 4 * 128, ar_cce, ar_ice},
             {sl_cc, sr_cc, sr_ic, sl_ci, sr_cce, sr_ice}, CONC_N, 6};
  R1.d[1] = {item_x, {vecs + 2 * 128, vecs + 5 * 128, vecs + 7 * 128, vecs + 8 * 128, nullptr, nullptr},
             {sl_ic, sr_ci, sr_si, sl_is, nullptr, nullptr}, ITEM_N, 4};
  R1.d[2] = {stu_x,     {vecs + 6 * 128, nullptr, nullptr, nullptr, nullptr, nullptr},
             {sl_si, nullptr, nullptr, nullptr, nullptr, nullptr}, STU_N, 1};
  R1.d[3] = {stu_raw_x, {vecs + 9 * 128, nullptr, nullptr, nullptr, nullptr, nullptr},
             {sr_is, nullptr, nullptr, nullptr, nullptr, nullptr}, STU_N, 1};
  mdots<<<dim3(256, 4), 256, 0, stream>>>(R1);

  // 6) c1, c2 (inter GATs on concept targets)
  gat_agg<<<(CONC_N + 3) / 4, 256, 0, stream>>>(offs0, srcs0, sl_cc, sr_cc,
                                                concWcc, nullptr, nullptr, c1buf, CONC_N);
  gat_agg<<<(CONC_N + 3) / 4, 256, 0, stream>>>(offs1, srcs1, sl_ic, sr_ic,
                                                itemWic, nullptr, nullptr, c2buf, CONC_N);

  // 7) scores that depend on c1/c2
  MDots R2;
  R2.d[0] = {c1buf, {al_cce, nullptr, nullptr, nullptr, nullptr, nullptr},
             {sl_cce, nullptr, nullptr, nullptr, nullptr, nullptr}, CONC_N, 1};
  R2.d[1] = {c2buf, {al_ice, nullptr, nullptr, nullptr, nullptr, nullptr},
             {sl_ice, nullptr, nullptr, nullptr, nullptr, nullptr}, CONC_N, 1};
  mdots<<<dim3(16, 2), 256, 0, stream>>>(R2);

  // 8) conc_fused = conc_x + e1 + e2
  gat_agg_dual<<<(CONC_N + 3) / 4, 256, 0, stream>>>(
      offs0, srcs0, sl_cce, sr_cce, c1buf, sl_ice, sr_ice, c2buf,
      conc_x, out_conc, CONC_N);

  // 9) item fusion
  gat_agg<<<(ITEM_N + 3) / 4, 256, 0, stream>>>(offs2, srcs2, sl_ci, sr_ci,
                                                concWci, nullptr, nullptr, i1buf, ITEM_N);
  gat_agg<<<(ITEM_N + 3) / 4, 256, 0, stream>>>(offs3, srcs3, sl_si, sr_si,
                                                stuWsi, item_x, i1buf, out_item, ITEM_N);

  // 10) student fusion
  gat_agg<<<(STU_N + 3) / 4, 256, 0, stream>>>(offs4, srcs4, sl_is, sr_is,
                                               itemWis, stu_raw_x, nullptr, out_stu, STU_N);
}

// Round 4
// 438.873 us; speedup vs baseline: 11.0209x; 1.1422x over previous
//
#include <hip/hip_runtime.h>

#define CONC_N 2000
#define ITEM_N 20000
#define STU_N  50000
#define NE_CC  40000
#define NE_IC  80000
#define NE_SI  1000000
#define TBUCK  382   // 63+63+79+79+98

typedef unsigned int uint;
typedef unsigned short ushort;

__device__ __forceinline__ ushort f2bf(float f) {
  uint u = __float_as_uint(f);
  uint r = (u + 0x7FFFu + ((u >> 16) & 1u)) >> 16;
  return (ushort)r;
}

// ---------------- misc small kernels ----------------

__global__ void zero_ints(int* __restrict__ p, int n) {
  int i = blockIdx.x * blockDim.x + threadIdx.x;
  if (i < n) p[i] = 0;
}

// v[k] = sum_j W[j*128+k] * a[j]   (projected attention vector W^T a)
struct ProjDesc { const float* W; const float* a; float* out; };
struct ProjDescs { ProjDesc d[10]; };
__global__ void proj_vecs(ProjDescs P) {
  ProjDesc d = P.d[blockIdx.x];
  int k = threadIdx.x;  // 128 threads
  float acc = 0.f;
  for (int j = 0; j < 128; ++j) acc += d.W[j * 128 + k] * d.a[j];
  d.out[k] = acc;
}

// multi-vector row dots, compile-time NV so everything stays in registers
template <int NV> struct MDotP { const float* x; const float* v[NV]; float* o[NV]; int n; };

template <int NV>
__global__ void mdotsT(MDotP<NV> d) {
  int lane = threadIdx.x & 63;
  int wid = (blockIdx.x * blockDim.x + threadIdx.x) >> 6;
  int nw = (gridDim.x * blockDim.x) >> 6;
  float va[NV], vb[NV];
  #pragma unroll
  for (int j = 0; j < NV; ++j) { va[j] = d.v[j][lane]; vb[j] = d.v[j][64 + lane]; }
  for (int r = wid; r < d.n; r += nw) {
    float x0 = d.x[r * 128 + lane], x1 = d.x[r * 128 + 64 + lane];
    #pragma unroll
    for (int j = 0; j < NV; ++j) {
      float a = x0 * va[j] + x1 * vb[j];
      #pragma unroll
      for (int o = 32; o; o >>= 1) a += __shfl_xor(a, o);
      if (lane == 0) d.o[j][r] = a;
    }
  }
}

// ---------------- CSR build via bucketed counting sort ----------------

struct CsrG {
  const int* dst; const int* src;
  unsigned* keys; int* srcs; int* offs;
  int E, n, shift, nbuck, tb, sb;
};
struct CsrGs { CsrG g[5]; };

__global__ void csr_count(CsrGs G, int* __restrict__ bcnt) {
  CsrG g = G.g[blockIdx.y];
  __shared__ int lcnt[128];
  int tid = threadIdx.x;
  if (tid < 128) lcnt[tid] = 0;
  __syncthreads();
  for (int e = blockIdx.x * blockDim.x + tid; e < g.E; e += gridDim.x * blockDim.x)
    atomicAdd(&lcnt[g.dst[e] >> g.shift], 1);
  __syncthreads();
  if (tid < g.nbuck && lcnt[tid] > 0) atomicAdd(&bcnt[g.tb + tid], lcnt[tid]);
}

__global__ __launch_bounds__(512) void csr_scan(CsrGs G, const int* __restrict__ bcnt,
                                                int* __restrict__ cur, int* __restrict__ bases) {
  __shared__ int lc[TBUCK];
  __shared__ int lb[TBUCK + 5];
  int tid = threadIdx.x;
  if (tid < TBUCK) lc[tid] = bcnt[tid];
  __syncthreads();
  if (tid == 0) {
    for (int gi = 0; gi < 5; ++gi) {
      CsrG g = G.g[gi];
      int run = 0;
      for (int b = 0; b < g.nbuck; ++b) { lb[g.sb + b] = run; run += lc[g.tb + b]; }
      lb[g.sb + g.nbuck] = run;
    }
  }
  __syncthreads();
  if (tid < TBUCK + 5) bases[tid] = lb[tid];
  if (tid < TBUCK) {
    int gi = 0;
    for (int k = 1; k < 5; ++k) if (tid >= G.g[k].tb) gi = k;
    cur[tid] = lb[tid + gi];
  }
  if (tid < 5) G.g[tid].offs[G.g[tid].n] = G.g[tid].E;
}

__global__ __launch_bounds__(256) void csr_partition(CsrGs G, int* __restrict__ cur) {
  CsrG g = G.g[blockIdx.y];
  __shared__ unsigned ck[4096];
  __shared__ unsigned char cb[4096];
  __shared__ int lcnt[128], lcur[128];
  int tid = threadIdx.x;
  unsigned dmask = (1u << g.shift) - 1;
  for (int c0 = blockIdx.x * 4096; c0 < g.E; c0 += gridDim.x * 4096) {
    if (tid < 128) lcnt[tid] = 0;
    __syncthreads();
    #pragma unroll
    for (int i = 0; i < 16; ++i) {
      int e = c0 + i * 256 + tid;
      if (e < g.E) {
        int d = g.dst[e], s = g.src[e];
        int b = d >> g.shift;
        ck[i * 256 + tid] = ((unsigned)(d & dmask) << 16) | (unsigned)s;
        cb[i * 256 + tid] = (unsigned char)b;
        atomicAdd(&lcnt[b], 1);
      } else cb[i * 256 + tid] = 255;
    }
    __syncthreads();
    if (tid < g.nbuck && lcnt[tid] > 0) lcur[tid] = atomicAdd(&cur[g.tb + tid], lcnt[tid]);
    __syncthreads();
    #pragma unroll
    for (int i = 0; i < 16; ++i) {
      int b = cb[i * 256 + tid];
      if (b != 255) {
        int pos = atomicAdd(&lcur[b], 1);
        g.keys[pos] = ck[i * 256 + tid];
      }
    }
    __syncthreads();
  }
}

__global__ __launch_bounds__(256) void csr_build(CsrGs G, const int* __restrict__ bases) {
  int bid = blockIdx.x;
  int gi = 0;
  for (int k = 1; k < 5; ++k) if (bid >= G.g[k].tb) gi = k;
  CsrG g = G.g[gi];
  int b = bid - g.tb;
  int base = bases[g.sb + b];
  int cnt = bases[g.sb + b + 1] - base;
  if (cnt > 16384) cnt = 16384;

  __shared__ unsigned lkeys[16384];
  __shared__ int lh[512], lex[512], lcu[512], wsum[4];
  int tid = threadIdx.x;
  lh[tid] = 0; lh[tid + 256] = 0;
  __syncthreads();
  for (int j = tid; j < cnt; j += 256) {
    unsigned k = g.keys[base + j];
    lkeys[j] = k;
    atomicAdd(&lh[k >> 16], 1);
  }
  __syncthreads();
  int a0 = lh[2 * tid], a1 = lh[2 * tid + 1];
  int pair = a0 + a1;
  int lane = tid & 63, wv = tid >> 6;
  int incl = pair;
  #pragma unroll
  for (int o = 1; o < 64; o <<= 1) {
    int y = __shfl_up(incl, o);
    if (lane >= o) incl += y;
  }
  if (lane == 63) wsum[wv] = incl;
  __syncthreads();
  if (tid == 0) {
    int s = 0;
    #pragma unroll
    for (int w = 0; w < 4; ++w) { int t = wsum[w]; wsum[w] = s; s += t; }
  }
  __syncthreads();
  int ep = wsum[wv] + incl - pair;
  lex[2 * tid] = ep;       lex[2 * tid + 1] = ep + a0;
  lcu[2 * tid] = ep;       lcu[2 * tid + 1] = ep + a0;
  __syncthreads();
  int dst0 = b << g.shift;
  int ndst = min(1 << g.shift, g.n - dst0);
  for (int dl = tid; dl < ndst; dl += 256) g.offs[dst0 + dl] = base + lex[dl];
  for (int j = tid; j < cnt; j += 256) {
    unsigned k = lkeys[j];
    int dl = k >> 16;
    int pos = atomicAdd(&lcu[dl], 1);
    g.srcs[base + pos] = (int)(k & 0xFFFFu);
  }
}

// ---------------- GEMM: Y[n,128] = X[n,128] @ W[128,128]^T, bf16 output ----

__global__ __launch_bounds__(256, 2) void gemm128_bf(const float* __restrict__ X,
                                                     const float* __restrict__ W,
                                                     ushort* __restrict__ Y, int n) {
  __shared__ float Xt[32 * 68];
  __shared__ float Wt[32 * 132];
  int tid = threadIdx.x;
  int cg = tid & 31;
  int rg = tid >> 5;
  int rowbase = blockIdx.x * 64;
  float acc[8][4];
  #pragma unroll
  for (int i = 0; i < 8; ++i)
    #pragma unroll
    for (int j = 0; j < 4; ++j) acc[i][j] = 0.f;

  for (int kc = 0; kc < 4; ++kc) {
    int k0 = kc * 32;
    #pragma unroll
    for (int i = 0; i < 2; ++i) {
      int s = tid + i * 256;
      int row = s >> 3, kk4 = s & 7;
      int gr = rowbase + row;
      float4 xv = make_float4(0.f, 0.f, 0.f, 0.f);
      if (gr < n) xv = *(const float4*)&X[gr * 128 + k0 + kk4 * 4];
      Xt[(kk4 * 4 + 0) * 68 + row] = xv.x;
      Xt[(kk4 * 4 + 1) * 68 + row] = xv.y;
      Xt[(kk4 * 4 + 2) * 68 + row] = xv.z;
      Xt[(kk4 * 4 + 3) * 68 + row] = xv.w;
    }
    #pragma unroll
    for (int i = 0; i < 4; ++i) {
      int s = tid + i * 256;
      int c = s >> 3, kk4 = s & 7;
      float4 wv = *(const float4*)&W[c * 128 + k0 + kk4 * 4];
      Wt[(kk4 * 4 + 0) * 132 + c] = wv.x;
      Wt[(kk4 * 4 + 1) * 132 + c] = wv.y;
      Wt[(kk4 * 4 + 2) * 132 + c] = wv.z;
      Wt[(kk4 * 4 + 3) * 132 + c] = wv.w;
    }
    __syncthreads();
    #pragma unroll 4
    for (int kk = 0; kk < 32; ++kk) {
      float4 x0 = *(const float4*)&Xt[kk * 68 + rg * 8];
      float4 x1 = *(const float4*)&Xt[kk * 68 + rg * 8 + 4];
      float4 wv = *(const float4*)&Wt[kk * 132 + cg * 4];
      #pragma unroll
      for (int j = 0; j < 4; ++j) {
        float w = (j == 0) ? wv.x : (j == 1) ? wv.y : (j == 2) ? wv.z : wv.w;
        acc[0][j] += x0.x * w;
        acc[1][j] += x0.y * w;
        acc[2][j] += x0.z * w;
        acc[3][j] += x0.w * w;
        acc[4][j] += x1.x * w;
        acc[5][j] += x1.y * w;
        acc[6][j] += x1.z * w;
        acc[7][j] += x1.w * w;
      }
    }
    __syncthreads();
  }
  #pragma unroll
  for (int i = 0; i < 8; ++i) {
    int gr = rowbase + rg * 8 + i;
    if (gr < n) {
      ushort4 o4;
      o4.x = f2bf(acc[i][0]); o4.y = f2bf(acc[i][1]);
      o4.z = f2bf(acc[i][2]); o4.w = f2bf(acc[i][3]);
      *(ushort4*)&Y[gr * 128 + cg * 4] = o4;
    }
  }
}

// ---------------- GAT aggregation (wave per target) ----------------
// bf16-gather variant: xl packed as 64 uints (2 bf16 each) per row.

__global__ void gat_agg_bf(const int* __restrict__ offs, const int* __restrict__ srcs,
                           const float* __restrict__ sl, const float* __restrict__ sr,
                           const uint* __restrict__ xl,
                           const float* __restrict__ base0, const float* __restrict__ base1,
                           float* __restrict__ out, int n_tgt) {
  int t = (blockIdx.x * blockDim.x + threadIdx.x) >> 6;
  if (t >= n_tgt) return;
  int lane = threadIdx.x & 63;
  int sbeg = offs[t], send = offs[t + 1];
  float srt = sr[t];
  float m = -1e30f;
  for (int i = sbeg + lane; i < send; i += 64) {
    float e = sl[srcs[i]] + srt;
    e = e > 0.f ? e : 0.2f * e;
    m = fmaxf(m, e);
  }
  #pragma unroll
  for (int o = 32; o; o >>= 1) m = fmaxf(m, __shfl_xor(m, o));
  float se = 0.f;
  for (int i = sbeg + lane; i < send; i += 64) {
    float e = sl[srcs[i]] + srt;
    e = e > 0.f ? e : 0.2f * e;
    se += __expf(e - m);
  }
  #pragma unroll
  for (int o = 32; o; o >>= 1) se += __shfl_xor(se, o);
  float inv = 1.f / (se + 1e-16f);
  float ax = 0.f, ay = 0.f;
  for (int i0 = sbeg; i0 < send; i0 += 64) {
    int cnt = min(64, send - i0);
    int s = 0; float wgt = 0.f;
    if (lane < cnt) {
      s = srcs[i0 + lane];
      float e = sl[s] + srt;
      e = e > 0.f ? e : 0.2f * e;
      wgt = __expf(e - m) * inv;
    }
    for (int j = 0; j < cnt; ++j) {
      int sj = __shfl(s, j);
      float wj = __shfl(wgt, j);
      uint u = xl[sj * 64 + lane];
      ax += wj * __uint_as_float(u << 16);
      ay += wj * __uint_as_float(u & 0xFFFF0000u);
    }
  }
  if (base0) { const float2 b = *(const float2*)&base0[t * 128 + lane * 2]; ax += b.x; ay += b.y; }
  if (base1) { const float2 b = *(const float2*)&base1[t * 128 + lane * 2]; ax += b.x; ay += b.y; }
  float2 o2; o2.x = ax; o2.y = ay;
  *(float2*)&out[t * 128 + lane * 2] = o2;
}

// fp32-gather dual (cc graph, gathers c1buf/c2buf), writes base + r1 + r2
__global__ void gat_agg_dual(const int* __restrict__ offs, const int* __restrict__ srcs,
                             const float* __restrict__ sl1, const float* __restrict__ sr1,
                             const float* __restrict__ xl1,
                             const float* __restrict__ sl2, const float* __restrict__ sr2,
                             const float* __restrict__ xl2,
                             const float* __restrict__ base,
                             float* __restrict__ out, int n_tgt) {
  int t = (blockIdx.x * blockDim.x + threadIdx.x) >> 6;
  if (t >= n_tgt) return;
  int lane = threadIdx.x & 63;
  int sbeg = offs[t], send = offs[t + 1];
  float srt1 = sr1[t], srt2 = sr2[t];
  float m1 = -1e30f, m2 = -1e30f;
  for (int i = sbeg + lane; i < send; i += 64) {
    int s = srcs[i];
    float e1 = sl1[s] + srt1; e1 = e1 > 0.f ? e1 : 0.2f * e1;
    float e2 = sl2[s] + srt2; e2 = e2 > 0.f ? e2 : 0.2f * e2;
    m1 = fmaxf(m1, e1); m2 = fmaxf(m2, e2);
  }
  #pragma unroll
  for (int o = 32; o; o >>= 1) {
    m1 = fmaxf(m1, __shfl_xor(m1, o));
    m2 = fmaxf(m2, __shfl_xor(m2, o));
  }
  float se1 = 0.f, se2 = 0.f;
  for (int i = sbeg + lane; i < send; i += 64) {
    int s = srcs[i];
    float e1 = sl1[s] + srt1; e1 = e1 > 0.f ? e1 : 0.2f * e1;
    float e2 = sl2[s] + srt2; e2 = e2 > 0.f ? e2 : 0.2f * e2;
    se1 += __expf(e1 - m1); se2 += __expf(e2 - m2);
  }
  #pragma unroll
  for (int o = 32; o; o >>= 1) {
    se1 += __shfl_xor(se1, o);
    se2 += __shfl_xor(se2, o);
  }
  float inv1 = 1.f / (se1 + 1e-16f), inv2 = 1.f / (se2 + 1e-16f);
  float ax = 0.f, ay = 0.f;
  for (int i0 = sbeg; i0 < send; i0 += 64) {
    int cnt = min(64, send - i0);
    int s = 0; float w1 = 0.f, w2 = 0.f;
    if (lane < cnt) {
      s = srcs[i0 + lane];
      float e1 = sl1[s] + srt1; e1 = e1 > 0.f ? e1 : 0.2f * e1;
      float e2 = sl2[s] + srt2; e2 = e2 > 0.f ? e2 : 0.2f * e2;
      w1 = __expf(e1 - m1) * inv1;
      w2 = __expf(e2 - m2) * inv2;
    }
    for (int j = 0; j < cnt; ++j) {
      int sj = __shfl(s, j);
      float wj1 = __shfl(w1, j);
      float wj2 = __shfl(w2, j);
      const float2 v1 = *(const float2*)&xl1[sj * 128 + lane * 2];
      const float2 v2 = *(const float2*)&xl2[sj * 128 + lane * 2];
      ax += wj1 * v1.x + wj2 * v2.x;
      ay += wj1 * v1.y + wj2 * v2.y;
    }
  }
  const float2 b = *(const float2*)&base[t * 128 + lane * 2];
  float2 o2; o2.x = ax + b.x; o2.y = ay + b.y;
  *(float2*)&out[t * 128 + lane * 2] = o2;
}

// ---------------- launch ----------------

extern "C" void kernel_launch(void* const* d_in, const int* in_sizes, int n_in,
                              void* d_out, int out_size, void* d_ws, size_t ws_size,
                              hipStream_t stream) {
  const float* stu_x     = (const float*)d_in[0];
  const float* item_x    = (const float*)d_in[1];
  const float* conc_x    = (const float*)d_in[2];
  const float* stu_raw_x = (const float*)d_in[3];
  const float* W_cc  = (const float*)d_in[4];
  const float* al_cc = (const float*)d_in[5];
  const float* ar_cc = (const float*)d_in[6];
  const float* W_ic  = (const float*)d_in[7];
  const float* al_ic = (const float*)d_in[8];
  const float* ar_ic = (const float*)d_in[9];
  const float* al_cce = (const float*)d_in[10];
  const float* ar_cce = (const float*)d_in[11];
  const float* al_ice = (const float*)d_in[12];
  const float* ar_ice = (const float*)d_in[13];
  const float* W_ci  = (const float*)d_in[14];
  const float* al_ci = (const float*)d_in[15];
  const float* ar_ci = (const float*)d_in[16];
  const float* W_si  = (const float*)d_in[17];
  const float* al_si = (const float*)d_in[18];
  const float* ar_si = (const float*)d_in[19];
  const float* W_is  = (const float*)d_in[22];
  const float* al_is = (const float*)d_in[23];
  const float* ar_is = (const float*)d_in[24];
  const int* cc_src  = (const int*)d_in[25];
  const int* cc_dst  = (const int*)d_in[26];
  const int* ic_item = (const int*)d_in[27];
  const int* ic_conc = (const int*)d_in[28];
  const int* si_stu  = (const int*)d_in[29];
  const int* si_item = (const int*)d_in[30];

  char* wsb = (char*)d_ws;
  size_t off = 0;
  auto alloc = [&](size_t bytes) -> void* {
    void* p = wsb + off;
    off = (off + bytes + 255) & ~(size_t)255;
    return p;
  };

  // bf16 W-product tables (gather sources), 256 B/row
  ushort* concWcc = (ushort*)alloc((size_t)CONC_N * 128 * 2);
  ushort* itemWic = (ushort*)alloc((size_t)ITEM_N * 128 * 2);
  ushort* concWci = (ushort*)alloc((size_t)CONC_N * 128 * 2);
  ushort* stuWsi  = (ushort*)alloc((size_t)STU_N  * 128 * 2);
  ushort* itemWis = (ushort*)alloc((size_t)ITEM_N * 128 * 2);
  float* c1buf   = (float*)alloc((size_t)CONC_N * 128 * 4);
  float* c2buf   = (float*)alloc((size_t)CONC_N * 128 * 4);
  float* i1buf   = (float*)alloc((size_t)ITEM_N * 128 * 4);
  float* vecs    = (float*)alloc(10 * 128 * 4);
  float* sl_cc  = (float*)alloc(CONC_N * 4);
  float* sr_cc  = (float*)alloc(CONC_N * 4);
  float* sl_ic  = (float*)alloc(ITEM_N * 4);
  float* sr_ic  = (float*)alloc(CONC_N * 4);
  float* sl_ci  = (float*)alloc(CONC_N * 4);
  float* sr_ci  = (float*)alloc(ITEM_N * 4);
  float* sl_si  = (float*)alloc(STU_N * 4);
  float* sr_si  = (float*)alloc(ITEM_N * 4);
  float* sl_is  = (float*)alloc(ITEM_N * 4);
  float* sr_is  = (float*)alloc(STU_N * 4);
  float* sl_cce = (float*)alloc(CONC_N * 4);
  float* sr_cce = (float*)alloc(CONC_N * 4);
  float* sl_ice = (float*)alloc(CONC_N * 4);
  float* sr_ice = (float*)alloc(CONC_N * 4);

  unsigned* keys0 = (unsigned*)alloc((size_t)NE_CC * 4);
  unsigned* keys1 = (unsigned*)alloc((size_t)NE_IC * 4);
  unsigned* keys2 = (unsigned*)alloc((size_t)NE_IC * 4);
  unsigned* keys3 = (unsigned*)alloc((size_t)NE_SI * 4);
  unsigned* keys4 = (unsigned*)alloc((size_t)NE_SI * 4);
  int* srcs0 = (int*)alloc((size_t)NE_CC * 4);
  int* srcs1 = (int*)alloc((size_t)NE_IC * 4);
  int* srcs2 = (int*)alloc((size_t)NE_IC * 4);
  int* srcs3 = (int*)alloc((size_t)NE_SI * 4);
  int* srcs4 = (int*)alloc((size_t)NE_SI * 4);
  int* offs0 = (int*)alloc((CONC_N + 1) * 4);
  int* offs1 = (int*)alloc((CONC_N + 1) * 4);
  int* offs2 = (int*)alloc((ITEM_N + 1) * 4);
  int* offs3 = (int*)alloc((ITEM_N + 1) * 4);
  int* offs4 = (int*)alloc((STU_N + 1) * 4);
  int* bcnt_all  = (int*)alloc(TBUCK * 4);
  int* cur_all   = (int*)alloc(TBUCK * 4);
  int* bases_all = (int*)alloc((TBUCK + 5) * 4);

  float* out = (float*)d_out;
  float* out_conc = out;
  float* out_item = out + (size_t)CONC_N * 128;
  float* out_stu  = out + (size_t)(CONC_N + ITEM_N) * 128;

  CsrGs G;
  G.g[0] = {cc_dst,  cc_src,  keys0, srcs0, offs0, NE_CC, CONC_N, 5, 63,   0,   0};
  G.g[1] = {ic_conc, ic_item, keys1, srcs1, offs1, NE_IC, CONC_N, 5, 63,  63,  64};
  G.g[2] = {ic_item, ic_conc, keys2, srcs2, offs2, NE_IC, ITEM_N, 8, 79, 126, 128};
  G.g[3] = {si_item, si_stu,  keys3, srcs3, offs3, NE_SI, ITEM_N, 8, 79, 205, 208};
  G.g[4] = {si_stu,  si_item, keys4, srcs4, offs4, NE_SI, STU_N,  9, 98, 284, 288};

  // 1) zero bucket counters
  zero_ints<<<2, 256, 0, stream>>>(bcnt_all, TBUCK);

  // 2) projected attention vectors
  ProjDescs P;
  P.d[0] = {W_cc, al_cc, vecs + 0 * 128};
  P.d[1] = {W_cc, ar_cc, vecs + 1 * 128};
  P.d[2] = {W_ic, al_ic, vecs + 2 * 128};
  P.d[3] = {W_ic, ar_ic, vecs + 3 * 128};
  P.d[4] = {W_ci, al_ci, vecs + 4 * 128};
  P.d[5] = {W_ci, ar_ci, vecs + 5 * 128};
  P.d[6] = {W_si, al_si, vecs + 6 * 128};
  P.d[7] = {W_si, ar_si, vecs + 7 * 128};
  P.d[8] = {W_is, al_is, vecs + 8 * 128};
  P.d[9] = {W_is, ar_is, vecs + 9 * 128};
  proj_vecs<<<10, 128, 0, stream>>>(P);

  // 3) CSR build
  csr_count<<<dim3(128, 5), 256, 0, stream>>>(G, bcnt_all);
  csr_scan<<<1, 512, 0, stream>>>(G, bcnt_all, cur_all, bases_all);
  csr_partition<<<dim3(120, 5), 256, 0, stream>>>(G, cur_all);
  csr_build<<<TBUCK, 256, 0, stream>>>(G, bases_all);

  // 4) linear transforms -> bf16 tables
  gemm128_bf<<<(CONC_N + 63) / 64, 256, 0, stream>>>(conc_x, W_cc, concWcc, CONC_N);
  gemm128_bf<<<(ITEM_N + 63) / 64, 256, 0, stream>>>(item_x, W_ic, itemWic, ITEM_N);
  gemm128_bf<<<(CONC_N + 63) / 64, 256, 0, stream>>>(conc_x, W_ci, concWci, CONC_N);
  gemm128_bf<<<(STU_N  + 63) / 64, 256, 0, stream>>>(stu_x,  W_si, stuWsi,  STU_N);
  gemm128_bf<<<(ITEM_N + 63) / 64, 256, 0, stream>>>(item_x, W_is, itemWis, ITEM_N);

  // 5) per-node attention scores (register-resident multi-dot)
  {
    MDotP<6> dc; dc.x = conc_x; dc.n = CONC_N;
    dc.v[0] = vecs + 0 * 128; dc.o[0] = sl_cc;
    dc.v[1] = vecs + 1 * 128; dc.o[1] = sr_cc;
    dc.v[2] = vecs + 3 * 128; dc.o[2] = sr_ic;
    dc.v[3] = vecs + 4 * 128; dc.o[3] = sl_ci;
    dc.v[4] = ar_cce;         dc.o[4] = sr_cce;
    dc.v[5] = ar_ice;         dc.o[5] = sr_ice;
    mdotsT<6><<<125, 256, 0, stream>>>(dc);

    MDotP<4> di; di.x = item_x; di.n = ITEM_N;
    di.v[0] = vecs + 2 * 128; di.o[0] = sl_ic;
    di.v[1] = vecs + 5 * 128; di.o[1] = sr_ci;
    di.v[2] = vecs + 7 * 128; di.o[2] = sr_si;
    di.v[3] = vecs + 8 * 128; di.o[3] = sl_is;
    mdotsT<4><<<512, 256, 0, stream>>>(di);

    MDotP<1> ds; ds.x = stu_x; ds.n = STU_N;
    ds.v[0] = vecs + 6 * 128; ds.o[0] = sl_si;
    mdotsT<1><<<1024, 256, 0, stream>>>(ds);

    MDotP<1> dr; dr.x = stu_raw_x; dr.n = STU_N;
    dr.v[0] = vecs + 9 * 128; dr.o[0] = sr_is;
    mdotsT<1><<<1024, 256, 0, stream>>>(dr);
  }

  // 6) c1, c2 (inter GATs on concept targets)
  gat_agg_bf<<<(CONC_N + 3) / 4, 256, 0, stream>>>(offs0, srcs0, sl_cc, sr_cc,
                                                   (const uint*)concWcc, nullptr, nullptr, c1buf, CONC_N);
  gat_agg_bf<<<(CONC_N + 3) / 4, 256, 0, stream>>>(offs1, srcs1, sl_ic, sr_ic,
                                                   (const uint*)itemWic, nullptr, nullptr, c2buf, CONC_N);

  // 7) scores that depend on c1/c2
  {
    MDotP<1> d1; d1.x = c1buf; d1.n = CONC_N; d1.v[0] = al_cce; d1.o[0] = sl_cce;
    mdotsT<1><<<125, 256, 0, stream>>>(d1);
    MDotP<1> d2; d2.x = c2buf; d2.n = CONC_N; d2.v[0] = al_ice; d2.o[0] = sl_ice;
    mdotsT<1><<<125, 256, 0, stream>>>(d2);
  }

  // 8) conc_fused = conc_x + e1 + e2
  gat_agg_dual<<<(CONC_N + 3) / 4, 256, 0, stream>>>(
      offs0, srcs0, sl_cce, sr_cce, c1buf, sl_ice, sr_ice, c2buf,
      conc_x, out_conc, CONC_N);

  // 9) item fusion
  gat_agg_bf<<<(ITEM_N + 3) / 4, 256, 0, stream>>>(offs2, srcs2, sl_ci, sr_ci,
                                                   (const uint*)concWci, nullptr, nullptr, i1buf, ITEM_N);
  gat_agg_bf<<<(ITEM_N + 3) / 4, 256, 0, stream>>>(offs3, srcs3, sl_si, sr_si,
                                                   (const uint*)stuWsi, item_x, i1buf, out_item, ITEM_N);

  // 10) student fusion
  gat_agg_bf<<<(STU_N + 3) / 4, 256, 0, stream>>>(offs4, srcs4, sl_is, sr_is,
                                                  (const uint*)itemWis, stu_raw_x, nullptr, out_stu, STU_N);
}

// Round 5
// 355.900 us; speedup vs baseline: 13.5903x; 1.2331x over previous
//
#include <hip/hip_runtime.h>

#define CONC_N 2000
#define ITEM_N 20000
#define STU_N  50000
#define NE_CC  40000
#define NE_IC  80000
#define NE_SI  1000000
#define TBUCK  382   // 63+63+79+79+98

typedef unsigned int uint;
typedef unsigned short ushort;

__device__ __forceinline__ ushort f2bf(float f) {
  uint u = __float_as_uint(f);
  uint r = (u + 0x7FFFu + ((u >> 16) & 1u)) >> 16;
  return (ushort)r;
}

// ---------------- misc small kernels ----------------

__global__ void zero_ints(int* __restrict__ p, int n) {
  int i = blockIdx.x * blockDim.x + threadIdx.x;
  if (i < n) p[i] = 0;
}

// v[k] = sum_j W[j*128+k] * a[j]   (projected attention vector W^T a)
struct ProjDesc { const float* W; const float* a; float* out; };
struct ProjDescs { ProjDesc d[10]; };
__global__ void proj_vecs(ProjDescs P) {
  ProjDesc d = P.d[blockIdx.x];
  int k = threadIdx.x;  // 128 threads
  float acc = 0.f;
  for (int j = 0; j < 128; ++j) acc += d.W[j * 128 + k] * d.a[j];
  d.out[k] = acc;
}

// multi-vector row dots, compile-time NV so everything stays in registers
template <int NV> struct MDotP { const float* x; const float* v[NV]; float* o[NV]; int n; };

template <int NV>
__global__ void mdotsT(MDotP<NV> d) {
  int lane = threadIdx.x & 63;
  int wid = (blockIdx.x * blockDim.x + threadIdx.x) >> 6;
  int nw = (gridDim.x * blockDim.x) >> 6;
  float va[NV], vb[NV];
  #pragma unroll
  for (int j = 0; j < NV; ++j) { va[j] = d.v[j][lane]; vb[j] = d.v[j][64 + lane]; }
  for (int r = wid; r < d.n; r += nw) {
    float x0 = d.x[r * 128 + lane], x1 = d.x[r * 128 + 64 + lane];
    #pragma unroll
    for (int j = 0; j < NV; ++j) {
      float a = x0 * va[j] + x1 * vb[j];
      #pragma unroll
      for (int o = 32; o; o >>= 1) a += __shfl_xor(a, o);
      if (lane == 0) d.o[j][r] = a;
    }
  }
}

// ---------------- CSR build via bucketed counting sort ----------------

struct CsrG {
  const int* dst; const int* src;
  unsigned* keys; int* srcs; int* offs;
  int E, n, shift, nbuck, tb, sb;
};
struct CsrGs { CsrG g[5]; };

__global__ void csr_count(CsrGs G, int* __restrict__ bcnt) {
  CsrG g = G.g[blockIdx.y];
  __shared__ int lcnt[128];
  int tid = threadIdx.x;
  if (tid < 128) lcnt[tid] = 0;
  __syncthreads();
  for (int e = blockIdx.x * blockDim.x + tid; e < g.E; e += gridDim.x * blockDim.x)
    atomicAdd(&lcnt[g.dst[e] >> g.shift], 1);
  __syncthreads();
  if (tid < g.nbuck && lcnt[tid] > 0) atomicAdd(&bcnt[g.tb + tid], lcnt[tid]);
}

__global__ __launch_bounds__(512) void csr_scan(CsrGs G, const int* __restrict__ bcnt,
                                                int* __restrict__ cur, int* __restrict__ bases) {
  __shared__ int lc[TBUCK];
  __shared__ int lb[TBUCK + 5];
  int tid = threadIdx.x;
  if (tid < TBUCK) lc[tid] = bcnt[tid];
  __syncthreads();
  if (tid == 0) {
    for (int gi = 0; gi < 5; ++gi) {
      CsrG g = G.g[gi];
      int run = 0;
      for (int b = 0; b < g.nbuck; ++b) { lb[g.sb + b] = run; run += lc[g.tb + b]; }
      lb[g.sb + g.nbuck] = run;
    }
  }
  __syncthreads();
  if (tid < TBUCK + 5) bases[tid] = lb[tid];
  if (tid < TBUCK) {
    int gi = 0;
    for (int k = 1; k < 5; ++k) if (tid >= G.g[k].tb) gi = k;
    cur[tid] = lb[tid + gi];
  }
  if (tid < 5) G.g[tid].offs[G.g[tid].n] = G.g[tid].E;
}

__global__ __launch_bounds__(256) void csr_partition(CsrGs G, int* __restrict__ cur) {
  CsrG g = G.g[blockIdx.y];
  __shared__ unsigned ck[4096];
  __shared__ unsigned char cb[4096];
  __shared__ int lcnt[128], lcur[128];
  int tid = threadIdx.x;
  unsigned dmask = (1u << g.shift) - 1;
  for (int c0 = blockIdx.x * 4096; c0 < g.E; c0 += gridDim.x * 4096) {
    if (tid < 128) lcnt[tid] = 0;
    __syncthreads();
    #pragma unroll
    for (int i = 0; i < 16; ++i) {
      int e = c0 + i * 256 + tid;
      if (e < g.E) {
        int d = g.dst[e], s = g.src[e];
        int b = d >> g.shift;
        ck[i * 256 + tid] = ((unsigned)(d & dmask) << 16) | (unsigned)s;
        cb[i * 256 + tid] = (unsigned char)b;
        atomicAdd(&lcnt[b], 1);
      } else cb[i * 256 + tid] = 255;
    }
    __syncthreads();
    if (tid < g.nbuck && lcnt[tid] > 0) lcur[tid] = atomicAdd(&cur[g.tb + tid], lcnt[tid]);
    __syncthreads();
    #pragma unroll
    for (int i = 0; i < 16; ++i) {
      int b = cb[i * 256 + tid];
      if (b != 255) {
        int pos = atomicAdd(&lcur[b], 1);
        g.keys[pos] = ck[i * 256 + tid];
      }
    }
    __syncthreads();
  }
}

__global__ __launch_bounds__(256) void csr_build(CsrGs G, const int* __restrict__ bases) {
  int bid = blockIdx.x;
  int gi = 0;
  for (int k = 1; k < 5; ++k) if (bid >= G.g[k].tb) gi = k;
  CsrG g = G.g[gi];
  int b = bid - g.tb;
  int base = bases[g.sb + b];
  int cnt = bases[g.sb + b + 1] - base;
  if (cnt > 16384) cnt = 16384;

  __shared__ unsigned lkeys[16384];
  __shared__ int lh[512], lex[512], lcu[512], wsum[4];
  int tid = threadIdx.x;
  lh[tid] = 0; lh[tid + 256] = 0;
  __syncthreads();
  for (int j = tid; j < cnt; j += 256) {
    unsigned k = g.keys[base + j];
    lkeys[j] = k;
    atomicAdd(&lh[k >> 16], 1);
  }
  __syncthreads();
  int a0 = lh[2 * tid], a1 = lh[2 * tid + 1];
  int pair = a0 + a1;
  int lane = tid & 63, wv = tid >> 6;
  int incl = pair;
  #pragma unroll
  for (int o = 1; o < 64; o <<= 1) {
    int y = __shfl_up(incl, o);
    if (lane >= o) incl += y;
  }
  if (lane == 63) wsum[wv] = incl;
  __syncthreads();
  if (tid == 0) {
    int s = 0;
    #pragma unroll
    for (int w = 0; w < 4; ++w) { int t = wsum[w]; wsum[w] = s; s += t; }
  }
  __syncthreads();
  int ep = wsum[wv] + incl - pair;
  lex[2 * tid] = ep;       lex[2 * tid + 1] = ep + a0;
  lcu[2 * tid] = ep;       lcu[2 * tid + 1] = ep + a0;
  __syncthreads();
  int dst0 = b << g.shift;
  int ndst = min(1 << g.shift, g.n - dst0);
  for (int dl = tid; dl < ndst; dl += 256) g.offs[dst0 + dl] = base + lex[dl];
  for (int j = tid; j < cnt; j += 256) {
    unsigned k = lkeys[j];
    int dl = k >> 16;
    int pos = atomicAdd(&lcu[dl], 1);
    g.srcs[base + pos] = (int)(k & 0xFFFFu);
  }
}

// ---------------- GEMM: Y[n,128] = X[n,128] @ W[128,128]^T, bf16 output ----

__global__ __launch_bounds__(256, 2) void gemm128_bf(const float* __restrict__ X,
                                                     const float* __restrict__ W,
                                                     ushort* __restrict__ Y, int n) {
  __shared__ float Xt[32 * 68];
  __shared__ float Wt[32 * 132];
  int tid = threadIdx.x;
  int cg = tid & 31;
  int rg = tid >> 5;
  int rowbase = blockIdx.x * 64;
  float acc[8][4];
  #pragma unroll
  for (int i = 0; i < 8; ++i)
    #pragma unroll
    for (int j = 0; j < 4; ++j) acc[i][j] = 0.f;

  for (int kc = 0; kc < 4; ++kc) {
    int k0 = kc * 32;
    #pragma unroll
    for (int i = 0; i < 2; ++i) {
      int s = tid + i * 256;
      int row = s >> 3, kk4 = s & 7;
      int gr = rowbase + row;
      float4 xv = make_float4(0.f, 0.f, 0.f, 0.f);
      if (gr < n) xv = *(const float4*)&X[gr * 128 + k0 + kk4 * 4];
      Xt[(kk4 * 4 + 0) * 68 + row] = xv.x;
      Xt[(kk4 * 4 + 1) * 68 + row] = xv.y;
      Xt[(kk4 * 4 + 2) * 68 + row] = xv.z;
      Xt[(kk4 * 4 + 3) * 68 + row] = xv.w;
    }
    #pragma unroll
    for (int i = 0; i < 4; ++i) {
      int s = tid + i * 256;
      int c = s >> 3, kk4 = s & 7;
      float4 wv = *(const float4*)&W[c * 128 + k0 + kk4 * 4];
      Wt[(kk4 * 4 + 0) * 132 + c] = wv.x;
      Wt[(kk4 * 4 + 1) * 132 + c] = wv.y;
      Wt[(kk4 * 4 + 2) * 132 + c] = wv.z;
      Wt[(kk4 * 4 + 3) * 132 + c] = wv.w;
    }
    __syncthreads();
    #pragma unroll 4
    for (int kk = 0; kk < 32; ++kk) {
      float4 x0 = *(const float4*)&Xt[kk * 68 + rg * 8];
      float4 x1 = *(const float4*)&Xt[kk * 68 + rg * 8 + 4];
      float4 wv = *(const float4*)&Wt[kk * 132 + cg * 4];
      #pragma unroll
      for (int j = 0; j < 4; ++j) {
        float w = (j == 0) ? wv.x : (j == 1) ? wv.y : (j == 2) ? wv.z : wv.w;
        acc[0][j] += x0.x * w;
        acc[1][j] += x0.y * w;
        acc[2][j] += x0.z * w;
        acc[3][j] += x0.w * w;
        acc[4][j] += x1.x * w;
        acc[5][j] += x1.y * w;
        acc[6][j] += x1.z * w;
        acc[7][j] += x1.w * w;
      }
    }
    __syncthreads();
  }
  #pragma unroll
  for (int i = 0; i < 8; ++i) {
    int gr = rowbase + rg * 8 + i;
    if (gr < n) {
      ushort4 o4;
      o4.x = f2bf(acc[i][0]); o4.y = f2bf(acc[i][1]);
      o4.z = f2bf(acc[i][2]); o4.w = f2bf(acc[i][3]);
      *(ushort4*)&Y[gr * 128 + cg * 4] = o4;
    }
  }
}

// ---------------- GAT aggregation (wave per target, uint4 gather) --------
// xl: bf16 rows packed as 64 uints. Wave = 4 row-groups x 16 lanes; each
// lane fetches uint4 (8 dims) so one instruction pulls 4 full rows (1 KB).

__global__ void gat_agg_bf(const int* __restrict__ offs, const int* __restrict__ srcs,
                           const float* __restrict__ sl, const float* __restrict__ sr,
                           const uint* __restrict__ xl,
                           const float* __restrict__ base0, const float* __restrict__ base1,
                           float* __restrict__ out, int n_tgt) {
  int t = (blockIdx.x * blockDim.x + threadIdx.x) >> 6;
  if (t >= n_tgt) return;
  int lane = threadIdx.x & 63;
  int sbeg = offs[t], send = offs[t + 1];
  float srt = sr[t];
  // online softmax (single pass: running max + rescaled sum)
  float m = -1e30f, se = 0.f;
  for (int i = sbeg + lane; i < send; i += 64) {
    float e = sl[srcs[i]] + srt;
    e = e > 0.f ? e : 0.2f * e;
    float mn = fmaxf(m, e);
    se = se * __expf(m - mn) + __expf(e - mn);
    m = mn;
  }
  #pragma unroll
  for (int o = 32; o; o >>= 1) {
    float m2 = __shfl_xor(m, o), s2 = __shfl_xor(se, o);
    float mn = fmaxf(m, m2);
    se = se * __expf(m - mn) + s2 * __expf(m2 - mn);
    m = mn;
  }
  float inv = 1.f / (se + 1e-16f);

  int g = lane & 15;   // d-slice: dims g*8 .. g*8+7
  int q = lane >> 4;   // row-group 0..3
  float acc[8];
  #pragma unroll
  for (int r = 0; r < 8; ++r) acc[r] = 0.f;

  for (int i0 = sbeg; i0 < send; i0 += 64) {
    int cnt = min(64, send - i0);
    int s = 0; float wgt = 0.f;
    if (lane < cnt) {
      s = srcs[i0 + lane];
      float e = sl[s] + srt;
      e = e > 0.f ? e : 0.2f * e;
      wgt = __expf(e - m) * inv;
    }
    int kmax = (cnt + 3) >> 2;
    for (int k = 0; k < kmax; ++k) {
      int ej = 4 * k + q;
      int sj = __shfl(s, ej);
      float wj = __shfl(wgt, ej);
      const uint4 u = *(const uint4*)&xl[(size_t)sj * 64 + g * 4];
      acc[0] += wj * __uint_as_float(u.x << 16);
      acc[1] += wj * __uint_as_float(u.x & 0xFFFF0000u);
      acc[2] += wj * __uint_as_float(u.y << 16);
      acc[3] += wj * __uint_as_float(u.y & 0xFFFF0000u);
      acc[4] += wj * __uint_as_float(u.z << 16);
      acc[5] += wj * __uint_as_float(u.z & 0xFFFF0000u);
      acc[6] += wj * __uint_as_float(u.w << 16);
      acc[7] += wj * __uint_as_float(u.w & 0xFFFF0000u);
    }
  }
  // reduce the 4 row-group partials
  #pragma unroll
  for (int r = 0; r < 8; ++r) {
    acc[r] += __shfl_xor(acc[r], 16);
    acc[r] += __shfl_xor(acc[r], 32);
  }
  if (lane < 16) {
    int d = t * 128 + g * 8;
    float4 a0 = make_float4(acc[0], acc[1], acc[2], acc[3]);
    float4 a1 = make_float4(acc[4], acc[5], acc[6], acc[7]);
    if (base0) {
      const float4 b0 = *(const float4*)&base0[d];
      const float4 b1 = *(const float4*)&base0[d + 4];
      a0.x += b0.x; a0.y += b0.y; a0.z += b0.z; a0.w += b0.w;
      a1.x += b1.x; a1.y += b1.y; a1.z += b1.z; a1.w += b1.w;
    }
    if (base1) {
      const float4 b0 = *(const float4*)&base1[d];
      const float4 b1 = *(const float4*)&base1[d + 4];
      a0.x += b0.x; a0.y += b0.y; a0.z += b0.z; a0.w += b0.w;
      a1.x += b1.x; a1.y += b1.y; a1.z += b1.z; a1.w += b1.w;
    }
    *(float4*)&out[d] = a0;
    *(float4*)&out[d + 4] = a1;
  }
}

// fp32-gather dual (cc graph, gathers c1buf/c2buf), writes base + r1 + r2
__global__ void gat_agg_dual(const int* __restrict__ offs, const int* __restrict__ srcs,
                             const float* __restrict__ sl1, const float* __restrict__ sr1,
                             const float* __restrict__ xl1,
                             const float* __restrict__ sl2, const float* __restrict__ sr2,
                             const float* __restrict__ xl2,
                             const float* __restrict__ base,
                             float* __restrict__ out, int n_tgt) {
  int t = (blockIdx.x * blockDim.x + threadIdx.x) >> 6;
  if (t >= n_tgt) return;
  int lane = threadIdx.x & 63;
  int sbeg = offs[t], send = offs[t + 1];
  float srt1 = sr1[t], srt2 = sr2[t];
  float m1 = -1e30f, m2 = -1e30f;
  for (int i = sbeg + lane; i < send; i += 64) {
    int s = srcs[i];
    float e1 = sl1[s] + srt1; e1 = e1 > 0.f ? e1 : 0.2f * e1;
    float e2 = sl2[s] + srt2; e2 = e2 > 0.f ? e2 : 0.2f * e2;
    m1 = fmaxf(m1, e1); m2 = fmaxf(m2, e2);
  }
  #pragma unroll
  for (int o = 32; o; o >>= 1) {
    m1 = fmaxf(m1, __shfl_xor(m1, o));
    m2 = fmaxf(m2, __shfl_xor(m2, o));
  }
  float se1 = 0.f, se2 = 0.f;
  for (int i = sbeg + lane; i < send; i += 64) {
    int s = srcs[i];
    float e1 = sl1[s] + srt1; e1 = e1 > 0.f ? e1 : 0.2f * e1;
    float e2 = sl2[s] + srt2; e2 = e2 > 0.f ? e2 : 0.2f * e2;
    se1 += __expf(e1 - m1); se2 += __expf(e2 - m2);
  }
  #pragma unroll
  for (int o = 32; o; o >>= 1) {
    se1 += __shfl_xor(se1, o);
    se2 += __shfl_xor(se2, o);
  }
  float inv1 = 1.f / (se1 + 1e-16f), inv2 = 1.f / (se2 + 1e-16f);
  float ax = 0.f, ay = 0.f;
  for (int i0 = sbeg; i0 < send; i0 += 64) {
    int cnt = min(64, send - i0);
    int s = 0; float w1 = 0.f, w2 = 0.f;
    if (lane < cnt) {
      s = srcs[i0 + lane];
      float e1 = sl1[s] + srt1; e1 = e1 > 0.f ? e1 : 0.2f * e1;
      float e2 = sl2[s] + srt2; e2 = e2 > 0.f ? e2 : 0.2f * e2;
      w1 = __expf(e1 - m1) * inv1;
      w2 = __expf(e2 - m2) * inv2;
    }
    for (int j = 0; j < cnt; ++j) {
      int sj = __shfl(s, j);
      float wj1 = __shfl(w1, j);
      float wj2 = __shfl(w2, j);
      const float2 v1 = *(const float2*)&xl1[sj * 128 + lane * 2];
      const float2 v2 = *(const float2*)&xl2[sj * 128 + lane * 2];
      ax += wj1 * v1.x + wj2 * v2.x;
      ay += wj1 * v1.y + wj2 * v2.y;
    }
  }
  const float2 b = *(const float2*)&base[t * 128 + lane * 2];
  float2 o2; o2.x = ax + b.x; o2.y = ay + b.y;
  *(float2*)&out[t * 128 + lane * 2] = o2;
}

// ---------------- launch ----------------

extern "C" void kernel_launch(void* const* d_in, const int* in_sizes, int n_in,
                              void* d_out, int out_size, void* d_ws, size_t ws_size,
                              hipStream_t stream) {
  const float* stu_x     = (const float*)d_in[0];
  const float* item_x    = (const float*)d_in[1];
  const float* conc_x    = (const float*)d_in[2];
  const float* stu_raw_x = (const float*)d_in[3];
  const float* W_cc  = (const float*)d_in[4];
  const float* al_cc = (const float*)d_in[5];
  const float* ar_cc = (const float*)d_in[6];
  const float* W_ic  = (const float*)d_in[7];
  const float* al_ic = (const float*)d_in[8];
  const float* ar_ic = (const float*)d_in[9];
  const float* al_cce = (const float*)d_in[10];
  const float* ar_cce = (const float*)d_in[11];
  const float* al_ice = (const float*)d_in[12];
  const float* ar_ice = (const float*)d_in[13];
  const float* W_ci  = (const float*)d_in[14];
  const float* al_ci = (const float*)d_in[15];
  const float* ar_ci = (const float*)d_in[16];
  const float* W_si  = (const float*)d_in[17];
  const float* al_si = (const float*)d_in[18];
  const float* ar_si = (const float*)d_in[19];
  const float* W_is  = (const float*)d_in[22];
  const float* al_is = (const float*)d_in[23];
  const float* ar_is = (const float*)d_in[24];
  const int* cc_src  = (const int*)d_in[25];
  const int* cc_dst  = (const int*)d_in[26];
  const int* ic_item = (const int*)d_in[27];
  const int* ic_conc = (const int*)d_in[28];
  const int* si_stu  = (const int*)d_in[29];
  const int* si_item = (const int*)d_in[30];

  char* wsb = (char*)d_ws;
  size_t off = 0;
  auto alloc = [&](size_t bytes) -> void* {
    void* p = wsb + off;
    off = (off + bytes + 255) & ~(size_t)255;
    return p;
  };

  // bf16 W-product tables (gather sources), 256 B/row
  ushort* concWcc = (ushort*)alloc((size_t)CONC_N * 128 * 2);
  ushort* itemWic = (ushort*)alloc((size_t)ITEM_N * 128 * 2);
  ushort* concWci = (ushort*)alloc((size_t)CONC_N * 128 * 2);
  ushort* stuWsi  = (ushort*)alloc((size_t)STU_N  * 128 * 2);
  ushort* itemWis = (ushort*)alloc((size_t)ITEM_N * 128 * 2);
  float* c1buf   = (float*)alloc((size_t)CONC_N * 128 * 4);
  float* c2buf   = (float*)alloc((size_t)CONC_N * 128 * 4);
  float* i1buf   = (float*)alloc((size_t)ITEM_N * 128 * 4);
  float* vecs    = (float*)alloc(10 * 128 * 4);
  float* sl_cc  = (float*)alloc(CONC_N * 4);
  float* sr_cc  = (float*)alloc(CONC_N * 4);
  float* sl_ic  = (float*)alloc(ITEM_N * 4);
  float* sr_ic  = (float*)alloc(CONC_N * 4);
  float* sl_ci  = (float*)alloc(CONC_N * 4);
  float* sr_ci  = (float*)alloc(ITEM_N * 4);
  float* sl_si  = (float*)alloc(STU_N * 4);
  float* sr_si  = (float*)alloc(ITEM_N * 4);
  float* sl_is  = (float*)alloc(ITEM_N * 4);
  float* sr_is  = (float*)alloc(STU_N * 4);
  float* sl_cce = (float*)alloc(CONC_N * 4);
  float* sr_cce = (float*)alloc(CONC_N * 4);
  float* sl_ice = (float*)alloc(CONC_N * 4);
  float* sr_ice = (float*)alloc(CONC_N * 4);

  unsigned* keys0 = (unsigned*)alloc((size_t)NE_CC * 4);
  unsigned* keys1 = (unsigned*)alloc((size_t)NE_IC * 4);
  unsigned* keys2 = (unsigned*)alloc((size_t)NE_IC * 4);
  unsigned* keys3 = (unsigned*)alloc((size_t)NE_SI * 4);
  unsigned* keys4 = (unsigned*)alloc((size_t)NE_SI * 4);
  int* srcs0 = (int*)alloc((size_t)NE_CC * 4);
  int* srcs1 = (int*)alloc((size_t)NE_IC * 4);
  int* srcs2 = (int*)alloc((size_t)NE_IC * 4);
  int* srcs3 = (int*)alloc((size_t)NE_SI * 4);
  int* srcs4 = (int*)alloc((size_t)NE_SI * 4);
  int* offs0 = (int*)alloc((CONC_N + 1) * 4);
  int* offs1 = (int*)alloc((CONC_N + 1) * 4);
  int* offs2 = (int*)alloc((ITEM_N + 1) * 4);
  int* offs3 = (int*)alloc((ITEM_N + 1) * 4);
  int* offs4 = (int*)alloc((STU_N + 1) * 4);
  int* bcnt_all  = (int*)alloc(TBUCK * 4);
  int* cur_all   = (int*)alloc(TBUCK * 4);
  int* bases_all = (int*)alloc((TBUCK + 5) * 4);

  float* out = (float*)d_out;
  float* out_conc = out;
  float* out_item = out + (size_t)CONC_N * 128;
  float* out_stu  = out + (size_t)(CONC_N + ITEM_N) * 128;

  CsrGs G;
  G.g[0] = {cc_dst,  cc_src,  keys0, srcs0, offs0, NE_CC, CONC_N, 5, 63,   0,   0};
  G.g[1] = {ic_conc, ic_item, keys1, srcs1, offs1, NE_IC, CONC_N, 5, 63,  63,  64};
  G.g[2] = {ic_item, ic_conc, keys2, srcs2, offs2, NE_IC, ITEM_N, 8, 79, 126, 128};
  G.g[3] = {si_item, si_stu,  keys3, srcs3, offs3, NE_SI, ITEM_N, 8, 79, 205, 208};
  G.g[4] = {si_stu,  si_item, keys4, srcs4, offs4, NE_SI, STU_N,  9, 98, 284, 288};

  // 1) zero bucket counters
  zero_ints<<<2, 256, 0, stream>>>(bcnt_all, TBUCK);

  // 2) projected attention vectors
  ProjDescs P;
  P.d[0] = {W_cc, al_cc, vecs + 0 * 128};
  P.d[1] = {W_cc, ar_cc, vecs + 1 * 128};
  P.d[2] = {W_ic, al_ic, vecs + 2 * 128};
  P.d[3] = {W_ic, ar_ic, vecs + 3 * 128};
  P.d[4] = {W_ci, al_ci, vecs + 4 * 128};
  P.d[5] = {W_ci, ar_ci, vecs + 5 * 128};
  P.d[6] = {W_si, al_si, vecs + 6 * 128};
  P.d[7] = {W_si, ar_si, vecs + 7 * 128};
  P.d[8] = {W_is, al_is, vecs + 8 * 128};
  P.d[9] = {W_is, ar_is, vecs + 9 * 128};
  proj_vecs<<<10, 128, 0, stream>>>(P);

  // 3) CSR build
  csr_count<<<dim3(128, 5), 256, 0, stream>>>(G, bcnt_all);
  csr_scan<<<1, 512, 0, stream>>>(G, bcnt_all, cur_all, bases_all);
  csr_partition<<<dim3(120, 5), 256, 0, stream>>>(G, cur_all);
  csr_build<<<TBUCK, 256, 0, stream>>>(G, bases_all);

  // 4) linear transforms -> bf16 tables
  gemm128_bf<<<(CONC_N + 63) / 64, 256, 0, stream>>>(conc_x, W_cc, concWcc, CONC_N);
  gemm128_bf<<<(ITEM_N + 63) / 64, 256, 0, stream>>>(item_x, W_ic, itemWic, ITEM_N);
  gemm128_bf<<<(CONC_N + 63) / 64, 256, 0, stream>>>(conc_x, W_ci, concWci, CONC_N);
  gemm128_bf<<<(STU_N  + 63) / 64, 256, 0, stream>>>(stu_x,  W_si, stuWsi,  STU_N);
  gemm128_bf<<<(ITEM_N + 63) / 64, 256, 0, stream>>>(item_x, W_is, itemWis, ITEM_N);

  // 5) per-node attention scores (register-resident multi-dot)
  {
    MDotP<6> dc; dc.x = conc_x; dc.n = CONC_N;
    dc.v[0] = vecs + 0 * 128; dc.o[0] = sl_cc;
    dc.v[1] = vecs + 1 * 128; dc.o[1] = sr_cc;
    dc.v[2] = vecs + 3 * 128; dc.o[2] = sr_ic;
    dc.v[3] = vecs + 4 * 128; dc.o[3] = sl_ci;
    dc.v[4] = ar_cce;         dc.o[4] = sr_cce;
    dc.v[5] = ar_ice;         dc.o[5] = sr_ice;
    mdotsT<6><<<125, 256, 0, stream>>>(dc);

    MDotP<4> di; di.x = item_x; di.n = ITEM_N;
    di.v[0] = vecs + 2 * 128; di.o[0] = sl_ic;
    di.v[1] = vecs + 5 * 128; di.o[1] = sr_ci;
    di.v[2] = vecs + 7 * 128; di.o[2] = sr_si;
    di.v[3] = vecs + 8 * 128; di.o[3] = sl_is;
    mdotsT<4><<<512, 256, 0, stream>>>(di);

    MDotP<1> ds; ds.x = stu_x; ds.n = STU_N;
    ds.v[0] = vecs + 6 * 128; ds.o[0] = sl_si;
    mdotsT<1><<<1024, 256, 0, stream>>>(ds);

    MDotP<1> dr; dr.x = stu_raw_x; dr.n = STU_N;
    dr.v[0] = vecs + 9 * 128; dr.o[0] = sr_is;
    mdotsT<1><<<1024, 256, 0, stream>>>(dr);
  }

  // 6) c1, c2 (inter GATs on concept targets)
  gat_agg_bf<<<(CONC_N + 3) / 4, 256, 0, stream>>>(offs0, srcs0, sl_cc, sr_cc,
                                                   (const uint*)concWcc, nullptr, nullptr, c1buf, CONC_N);
  gat_agg_bf<<<(CONC_N + 3) / 4, 256, 0, stream>>>(offs1, srcs1, sl_ic, sr_ic,
                                                   (const uint*)itemWic, nullptr, nullptr, c2buf, CONC_N);

  // 7) scores that depend on c1/c2
  {
    MDotP<1> d1; d1.x = c1buf; d1.n = CONC_N; d1.v[0] = al_cce; d1.o[0] = sl_cce;
    mdotsT<1><<<125, 256, 0, stream>>>(d1);
    MDotP<1> d2; d2.x = c2buf; d2.n = CONC_N; d2.v[0] = al_ice; d2.o[0] = sl_ice;
    mdotsT<1><<<125, 256, 0, stream>>>(d2);
  }

  // 8) conc_fused = conc_x + e1 + e2
  gat_agg_dual<<<(CONC_N + 3) / 4, 256, 0, stream>>>(
      offs0, srcs0, sl_cce, sr_cce, c1buf, sl_ice, sr_ice, c2buf,
      conc_x, out_conc, CONC_N);

  // 9) item fusion
  gat_agg_bf<<<(ITEM_N + 3) / 4, 256, 0, stream>>>(offs2, srcs2, sl_ci, sr_ci,
                                                   (const uint*)concWci, nullptr, nullptr, i1buf, ITEM_N);
  gat_agg_bf<<<(ITEM_N + 3) / 4, 256, 0, stream>>>(offs3, srcs3, sl_si, sr_si,
                                                   (const uint*)stuWsi, item_x, i1buf, out_item, ITEM_N);

  // 10) student fusion
  gat_agg_bf<<<(STU_N + 3) / 4, 256, 0, stream>>>(offs4, srcs4, sl_is, sr_is,
                                                  (const uint*)itemWis, stu_raw_x, nullptr, out_stu, STU_N);
}